// Round 23
// baseline (390.242 us; speedup 1.0000x reference)
//
#include <hip/hip_runtime.h>
#include <hip/hip_bf16.h>
#include <math.h>

#define TT 64
#define NN 2000
#define FIN 32
#define HH 64
#define CC 10
#define EE 32000
#define ETOT 34000   // E + N self loops
#define THL 4096     // T*H
#define EPSBN 1e-5f
#define NB 16        // nodes per GRU block

// ---------------- workspace layout (float offsets) ----------------
#define OFF_WC   0u          // WCh bf16 [2048][2048]
#define OFF_XA   4000000u    // 8,192,000  [N,T,H] fp32
#define OFF_XB   12192000u   // 8,192,000  (x_agg bf16 C; then xw bf16 scratch)
#define OFF_XC   20384000u   // 8,192,000  (first: XAh_t bf16 [4096][2048]; then fusion out fp32)
#define OFF_DEG  28576000u   // 2048
#define OFF_H1   28578048u   // 128,000 (unused)
#define OFF_CNT  28706048u   // int 2048
#define OFF_CUR  28708096u   // int 2048
#define OFF_OFF  28710144u   // int 2064
#define OFF_CSRS 28712208u   // int 34016
#define OFF_CSRN 28746224u   // float 34016
#define OFF_HST  28780240u   // float 128,000  (GRU h-state)

typedef __attribute__((ext_vector_type(8))) short short8v;
typedef __attribute__((ext_vector_type(4))) float f32x4;

__device__ __forceinline__ float fsigmoid(float x) { return 1.f / (1.f + __expf(-x)); }
__device__ __forceinline__ float ftanh(float x) {
    float e = __expf(2.f * x);
    return (e - 1.f) / (e + 1.f);
}
__device__ __forceinline__ unsigned short f2bf(float f) {
    __hip_bfloat16 h = __float2bfloat16(f);
    return *reinterpret_cast<unsigned short*>(&h);
}
__device__ __forceinline__ float bf2f(unsigned short u) {
    unsigned int x = ((unsigned int)u) << 16;
    return __int_as_float(x);
}
// async global->LDS, 16B per lane; LDS dest = wave-uniform base + lane*16 (linear)
__device__ __forceinline__ void gload_lds16(const unsigned short* g, unsigned short* l) {
    __builtin_amdgcn_global_load_lds(
        (const __attribute__((address_space(1))) unsigned int*)g,
        (__attribute__((address_space(3))) unsigned int*)l,
        16, 0, 0);
}

// ---------------- CSR build ----------------
__global__ void k_zero(int* cnt, int* cur, float* deg) {
    int i = blockIdx.x * 256 + threadIdx.x;
    if (i < 2048) { cnt[i] = 0; cur[i] = 0; deg[i] = 0.f; }
}

__global__ void k_count(const int* __restrict__ ei, const float* __restrict__ ew,
                        int* cnt, float* deg) {
    int e = blockIdx.x * 256 + threadIdx.x;
    if (e < ETOT) {
        int dst; float w;
        if (e < EE) { dst = ei[EE + e]; w = ew[e]; }
        else        { dst = e - EE;     w = 1.f; }
        atomicAdd(&cnt[dst], 1);
        atomicAdd(&deg[dst], w);
    }
}

__global__ __launch_bounds__(1024) void k_scan(const int* __restrict__ cnt, int* off) {
    __shared__ int s[2048];
    int tid = threadIdx.x;
    s[tid]        = (tid        < NN) ? cnt[tid]        : 0;
    s[tid + 1024] = (tid + 1024 < NN) ? cnt[tid + 1024] : 0;
    __syncthreads();
    for (int d = 1; d < 2048; d <<= 1) {
        int idx = (tid + 1) * (d << 1) - 1;
        if (idx < 2048) s[idx] += s[idx - d];
        __syncthreads();
    }
    if (tid == 0) s[2047] = 0;
    __syncthreads();
    for (int d = 1024; d >= 1; d >>= 1) {
        int idx = (tid + 1) * (d << 1) - 1;
        if (idx < 2048) { int t = s[idx - d]; s[idx - d] = s[idx]; s[idx] += t; }
        __syncthreads();
    }
    off[tid] = s[tid];
    off[tid + 1024] = s[tid + 1024];
}

__global__ void k_fill(const int* __restrict__ ei, const float* __restrict__ ew,
                       const float* __restrict__ deg, const int* __restrict__ off,
                       int* cur, int* csr_src, float* csr_nrm) {
    int e = blockIdx.x * 256 + threadIdx.x;
    if (e < ETOT) {
        int src, dst; float w;
        if (e < EE) { src = ei[e]; dst = ei[EE + e]; w = ew[e]; }
        else        { src = dst = e - EE;            w = 1.f; }
        float ds = rsqrtf(fmaxf(deg[src], 1e-12f));
        float dd = rsqrtf(fmaxf(deg[dst], 1e-12f));
        int pos = off[dst] + atomicAdd(&cur[dst], 1);
        csr_src[pos] = src;
        csr_nrm[pos] = ds * w * dd;
    }
}

// ---------------- softmax over causal_weight rows -> bf16 WCh [2048 stride] ----------------
__global__ __launch_bounds__(256) void k_softmax(const float* __restrict__ CW,
                                                 unsigned short* __restrict__ WCH) {
    __shared__ float row[NN];
    __shared__ float red[256];
    int r = blockIdx.x, tid = threadIdx.x;
    const float* in = CW + (size_t)r * NN;
    float mx = -1e30f;
    for (int i = tid; i < NN; i += 256) { float v = in[i]; row[i] = v; mx = fmaxf(mx, v); }
    red[tid] = mx; __syncthreads();
    for (int s = 128; s > 0; s >>= 1) {
        if (tid < s) red[tid] = fmaxf(red[tid], red[tid + s]);
        __syncthreads();
    }
    mx = red[0]; __syncthreads();
    float sm = 0.f;
    for (int i = tid; i < NN; i += 256) { float e = __expf(row[i] - mx); row[i] = e; sm += e; }
    red[tid] = sm; __syncthreads();
    for (int s = 128; s > 0; s >>= 1) {
        if (tid < s) red[tid] += red[tid + s];
        __syncthreads();
    }
    float inv = 1.f / red[0];
    unsigned short* out = WCH + (size_t)r * 2048;
    for (int i = tid; i < 2048; i += 256)
        out[i] = (i < NN) ? f2bf(row[i] * inv) : (unsigned short)0;
}

// ---------------- lin_in as tiled GEMM: rows=(n,t), K=32, 64 cols ----------------
__global__ __launch_bounds__(256) void k_lin2(const float* __restrict__ XS,
                                              const float* __restrict__ W,
                                              const float* __restrict__ b,
                                              float* __restrict__ OUT) {
    __shared__ float Wt[FIN][68];   // [k][o]
    __shared__ float As[FIN][68];   // [k][row]
    int tid = threadIdx.x;
    int n = blockIdx.x;
    for (int i = tid; i < HH * FIN; i += 256) { int o = i >> 5, k = i & 31; Wt[k][o] = W[i]; }
    int row = tid >> 2, kq = tid & 3;   // row = t
    {
        const float4* src = (const float4*)(XS + ((size_t)row * NN + n) * FIN + kq * 8);
        float4 v0 = src[0], v1 = src[1];
        As[kq * 8 + 0][row] = v0.x; As[kq * 8 + 1][row] = v0.y;
        As[kq * 8 + 2][row] = v0.z; As[kq * 8 + 3][row] = v0.w;
        As[kq * 8 + 4][row] = v1.x; As[kq * 8 + 5][row] = v1.y;
        As[kq * 8 + 6][row] = v1.z; As[kq * 8 + 7][row] = v1.w;
    }
    __syncthreads();
    int tx = tid & 15, ty = tid >> 4;
    float acc[4][4] = {};
#pragma unroll
    for (int k = 0; k < FIN; ++k) {
        float4 av = *(const float4*)&As[k][ty * 4];
        float4 wv = *(const float4*)&Wt[k][tx * 4];
        acc[0][0] += av.x * wv.x; acc[0][1] += av.x * wv.y; acc[0][2] += av.x * wv.z; acc[0][3] += av.x * wv.w;
        acc[1][0] += av.y * wv.x; acc[1][1] += av.y * wv.y; acc[1][2] += av.y * wv.z; acc[1][3] += av.y * wv.w;
        acc[2][0] += av.z * wv.x; acc[2][1] += av.z * wv.y; acc[2][2] += av.z * wv.z; acc[2][3] += av.z * wv.w;
        acc[3][0] += av.w * wv.x; acc[3][1] += av.w * wv.y; acc[3][2] += av.w * wv.z; acc[3][3] += av.w * wv.w;
    }
    float4 bv = *(const float4*)(b + tx * 4);
#pragma unroll
    for (int ii = 0; ii < 4; ++ii) {
        float4 o;
        o.x = fmaxf(acc[ii][0] + bv.x, 0.f);
        o.y = fmaxf(acc[ii][1] + bv.y, 0.f);
        o.z = fmaxf(acc[ii][2] + bv.z, 0.f);
        o.w = fmaxf(acc[ii][3] + bv.w, 0.f);
        *(float4*)(OUT + ((size_t)n * TT + ty * 4 + ii) * HH + tx * 4) = o;
    }
}

// ---------------- transpose + bf16 cast ----------------
__global__ __launch_bounds__(256) void k_tr(const float* __restrict__ X,
                                            unsigned short* __restrict__ XT) {
    __shared__ unsigned short tile[64][65];
    int cb = blockIdx.x * 64;
    int kb = blockIdx.y * 64;
    int tid = threadIdx.x;
    int r = tid >> 2, cq = tid & 3;
    const float4* src = (const float4*)(X + (size_t)(kb + r) * THL + cb + cq * 16);
#pragma unroll
    for (int j = 0; j < 4; ++j) {
        float4 v = src[j];
        tile[cq * 16 + j * 4 + 0][r] = f2bf(v.x);
        tile[cq * 16 + j * 4 + 1][r] = f2bf(v.y);
        tile[cq * 16 + j * 4 + 2][r] = f2bf(v.z);
        tile[cq * 16 + j * 4 + 3][r] = f2bf(v.w);
    }
    __syncthreads();
    int cl = tid >> 2, kq = tid & 3;
    unsigned short tmp[16];
#pragma unroll
    for (int j = 0; j < 16; ++j) tmp[j] = tile[cl][kq * 16 + j];
    unsigned short* dst = XT + (size_t)(cb + cl) * 2048 + kb + kq * 16;
    *(uint4*)dst = *(uint4*)tmp;
    *(uint4*)(dst + 8) = *(uint4*)(tmp + 8);
}

// ---------------- bf16 MFMA GEMM: C(bf16)[2000,4096] = WCh @ X (via XAh_t) — R22 proven ----------------
__global__ __launch_bounds__(256, 1) void k_gemm_bf(const unsigned short* __restrict__ A,
                                                    const unsigned short* __restrict__ B,
                                                    unsigned short* __restrict__ CH) {
    __shared__ unsigned short As[128][64];   // 16 KB, linear
    __shared__ unsigned short Bs[128][64];
    int tid = threadIdx.x;
    int mb = blockIdx.y * 128, nb = blockIdx.x * 128;
    int w = tid >> 6, lane = tid & 63;
    int wr = w >> 1, wc = w & 1;
    int l15 = lane & 15, l4 = lane >> 4;
    f32x4 acc[4][4] = {};
    int r_base = w * 8 + (lane >> 3);
    int colu = (lane & 7) * 8;
    for (int kt = 0; kt < 32; ++kt) {
        __syncthreads();
#pragma unroll
        for (int c = 0; c < 4; ++c) {
            int row = c * 32 + r_base;
            gload_lds16(A + (size_t)(mb + row) * 2048 + kt * 64 + colu, &As[c * 32 + w * 8][0]);
            gload_lds16(B + (size_t)(nb + row) * 2048 + kt * 64 + colu, &Bs[c * 32 + w * 8][0]);
        }
        __syncthreads();
#pragma unroll
        for (int kk = 0; kk < 2; ++kk) {
            short8v af[4], bfr[4];
#pragma unroll
            for (int f = 0; f < 4; ++f) {
                af[f]  = *(const short8v*)&As[wr * 64 + f * 16 + l15][kk * 32 + l4 * 8];
                bfr[f] = *(const short8v*)&Bs[wc * 64 + f * 16 + l15][kk * 32 + l4 * 8];
            }
#pragma unroll
            for (int fm = 0; fm < 4; ++fm)
#pragma unroll
                for (int fn = 0; fn < 4; ++fn)
                    acc[fm][fn] = __builtin_amdgcn_mfma_f32_16x16x32_bf16(af[fm], bfr[fn], acc[fm][fn], 0, 0, 0);
        }
    }
    unsigned short* epi = (unsigned short*)(&As[0][0]) + (size_t)w * (16 * 72);
    int erow8 = lane >> 3;
    int ecol8 = lane & 7;
#pragma unroll
    for (int fm = 0; fm < 4; ++fm) {
        __syncthreads();
#pragma unroll
        for (int fn = 0; fn < 4; ++fn)
#pragma unroll
            for (int rr = 0; rr < 4; ++rr)
                epi[(l4 * 4 + rr) * 72 + fn * 16 + l15] = f2bf(acc[fm][fn][rr]);
        __syncthreads();
#pragma unroll
        for (int rh = 0; rh < 2; ++rh) {
            int lrow = rh * 8 + erow8;
            int grow = mb + wr * 64 + fm * 16 + lrow;
            if (grow < NN) {
                *(uint4*)(CH + (size_t)grow * THL + nb + wc * 64 + ecol8 * 8)
                    = *(const uint4*)&epi[lrow * 72 + ecol8 * 8];
            }
        }
    }
}

// ---------------- fusion as tiled GEMM: K=128 (X fp32 + XAgg bf16), 64 cols ----------------
__global__ __launch_bounds__(256) void k_fus2(const float* __restrict__ X,
                                              const unsigned short* __restrict__ XAH,
                                              const float* __restrict__ W,
                                              const float* __restrict__ b,
                                              float* __restrict__ OUT) {
    __shared__ float Wt[2 * HH][68];
    __shared__ float As[HH][68];
    int tid = threadIdx.x;
    size_t r0 = (size_t)blockIdx.x * 64;
    for (int i = tid; i < HH * 2 * HH; i += 256) { int o = i >> 7, k = i & 127; Wt[k][o] = W[i]; }
    int row = tid >> 2, kq = tid & 3;
    int tx = tid & 15, ty = tid >> 4;
    float acc[4][4] = {};
    __syncthreads();
    {
        const float4* src = (const float4*)(X + (r0 + row) * HH + kq * 16);
#pragma unroll
        for (int j = 0; j < 4; ++j) {
            float4 v = src[j];
            As[kq * 16 + j * 4 + 0][row] = v.x;
            As[kq * 16 + j * 4 + 1][row] = v.y;
            As[kq * 16 + j * 4 + 2][row] = v.z;
            As[kq * 16 + j * 4 + 3][row] = v.w;
        }
    }
    __syncthreads();
#pragma unroll
    for (int k = 0; k < HH; ++k) {
        float4 av = *(const float4*)&As[k][ty * 4];
        float4 wv = *(const float4*)&Wt[k][tx * 4];
        acc[0][0] += av.x * wv.x; acc[0][1] += av.x * wv.y; acc[0][2] += av.x * wv.z; acc[0][3] += av.x * wv.w;
        acc[1][0] += av.y * wv.x; acc[1][1] += av.y * wv.y; acc[1][2] += av.y * wv.z; acc[1][3] += av.y * wv.w;
        acc[2][0] += av.z * wv.x; acc[2][1] += av.z * wv.y; acc[2][2] += av.z * wv.z; acc[2][3] += av.z * wv.w;
        acc[3][0] += av.w * wv.x; acc[3][1] += av.w * wv.y; acc[3][2] += av.w * wv.z; acc[3][3] += av.w * wv.w;
    }
    __syncthreads();
    {
        const uint4* s = (const uint4*)(XAH + (r0 + row) * HH + kq * 16);
        uint4 u0 = s[0], u1 = s[1];
        unsigned short us[16];
        *(uint4*)us = u0; *(uint4*)(us + 8) = u1;
#pragma unroll
        for (int j = 0; j < 16; ++j)
            As[kq * 16 + j][row] = bf2f(us[j]);
    }
    __syncthreads();
#pragma unroll
    for (int k = 0; k < HH; ++k) {
        float4 av = *(const float4*)&As[k][ty * 4];
        float4 wv = *(const float4*)&Wt[HH + k][tx * 4];
        acc[0][0] += av.x * wv.x; acc[0][1] += av.x * wv.y; acc[0][2] += av.x * wv.z; acc[0][3] += av.x * wv.w;
        acc[1][0] += av.y * wv.x; acc[1][1] += av.y * wv.y; acc[1][2] += av.y * wv.z; acc[1][3] += av.y * wv.w;
        acc[2][0] += av.z * wv.x; acc[2][1] += av.z * wv.y; acc[2][2] += av.z * wv.z; acc[2][3] += av.z * wv.w;
        acc[3][0] += av.w * wv.x; acc[3][1] += av.w * wv.y; acc[3][2] += av.w * wv.z; acc[3][3] += av.w * wv.w;
    }
    float4 bv = *(const float4*)(b + tx * 4);
#pragma unroll
    for (int ii = 0; ii < 4; ++ii) {
        float4 o;
        o.x = fmaxf(acc[ii][0] + bv.x, 0.f);
        o.y = fmaxf(acc[ii][1] + bv.y, 0.f);
        o.z = fmaxf(acc[ii][2] + bv.z, 0.f);
        o.w = fmaxf(acc[ii][3] + bv.w, 0.f);
        *(float4*)(OUT + (r0 + ty * 4 + ii) * HH + tx * 4) = o;
    }
}

// ---------------- GCN xw as tiled GEMM: K=64, 64 cols, bf16 output ----------------
__global__ __launch_bounds__(256) void k_xw2(const float* __restrict__ IN,
                                             const float* __restrict__ W,
                                             unsigned short* __restrict__ OUT) {
    __shared__ float Wt[HH][68];
    __shared__ float As[HH][68];
    int tid = threadIdx.x;
    size_t r0 = (size_t)blockIdx.x * 64;
    for (int i = tid; i < HH * HH; i += 256) { int o = i >> 6, k = i & 63; Wt[k][o] = W[i]; }
    int row = tid >> 2, kq = tid & 3;
    {
        const float4* src = (const float4*)(IN + (r0 + row) * HH + kq * 16);
#pragma unroll
        for (int j = 0; j < 4; ++j) {
            float4 v = src[j];
            As[kq * 16 + j * 4 + 0][row] = v.x;
            As[kq * 16 + j * 4 + 1][row] = v.y;
            As[kq * 16 + j * 4 + 2][row] = v.z;
            As[kq * 16 + j * 4 + 3][row] = v.w;
        }
    }
    __syncthreads();
    int tx = tid & 15, ty = tid >> 4;
    float acc[4][4] = {};
#pragma unroll
    for (int k = 0; k < HH; ++k) {
        float4 av = *(const float4*)&As[k][ty * 4];
        float4 wv = *(const float4*)&Wt[k][tx * 4];
        acc[0][0] += av.x * wv.x; acc[0][1] += av.x * wv.y; acc[0][2] += av.x * wv.z; acc[0][3] += av.x * wv.w;
        acc[1][0] += av.y * wv.x; acc[1][1] += av.y * wv.y; acc[1][2] += av.y * wv.z; acc[1][3] += av.y * wv.w;
        acc[2][0] += av.z * wv.x; acc[2][1] += av.z * wv.y; acc[2][2] += av.z * wv.z; acc[2][3] += av.z * wv.w;
        acc[3][0] += av.w * wv.x; acc[3][1] += av.w * wv.y; acc[3][2] += av.w * wv.z; acc[3][3] += av.w * wv.w;
    }
#pragma unroll
    for (int ii = 0; ii < 4; ++ii) {
        unsigned int p0 = (unsigned int)f2bf(acc[ii][0]) | ((unsigned int)f2bf(acc[ii][1]) << 16);
        unsigned int p1 = (unsigned int)f2bf(acc[ii][2]) | ((unsigned int)f2bf(acc[ii][3]) << 16);
        uint2 pk; pk.x = p0; pk.y = p1;
        *(uint2*)(OUT + (r0 + ty * 4 + ii) * HH + tx * 4) = pk;
    }
}

// ---------------- GCN aggregate (CSR, bf16 in) + bias + BN + relu ----------------
__global__ __launch_bounds__(256) void k_agg(const unsigned short* __restrict__ XW,
                                             const int* __restrict__ off,
                                             const int* __restrict__ csr_src,
                                             const float* __restrict__ csr_nrm,
                                             const float* __restrict__ bias,
                                             const float* __restrict__ g,
                                             const float* __restrict__ bb,
                                             const float* __restrict__ m,
                                             const float* __restrict__ v,
                                             float* __restrict__ OUT) {
    int dst = blockIdx.x, ch = blockIdx.y, tid = threadIdx.x;
    int base = ch * 1024 + tid * 4;
    float4 acc = make_float4(0.f, 0.f, 0.f, 0.f);
    int beg = off[dst], end = off[dst + 1];
    for (int e = beg; e < end; ++e) {
        int src = csr_src[e];
        float w = csr_nrm[e];
        uint2 u = *(const uint2*)(XW + (size_t)src * THL + base);
        acc.x += w * bf2f((unsigned short)(u.x & 0xffff));
        acc.y += w * bf2f((unsigned short)(u.x >> 16));
        acc.z += w * bf2f((unsigned short)(u.y & 0xffff));
        acc.w += w * bf2f((unsigned short)(u.y >> 16));
    }
    int h0 = base & 63;
    float4 bs = *(const float4*)(bias + h0);
    float4 gv = *(const float4*)(g + h0);
    float4 vv = *(const float4*)(v + h0);
    float4 mv = *(const float4*)(m + h0);
    float4 bv = *(const float4*)(bb + h0);
    float4 o;
    o.x = fmaxf((acc.x + bs.x - mv.x) * rsqrtf(vv.x + EPSBN) * gv.x + bv.x, 0.f);
    o.y = fmaxf((acc.y + bs.y - mv.y) * rsqrtf(vv.y + EPSBN) * gv.y + bv.y, 0.f);
    o.z = fmaxf((acc.z + bs.z - mv.z) * rsqrtf(vv.z + EPSBN) * gv.z + bv.z, 0.f);
    o.w = fmaxf((acc.w + bs.w - mv.w) * rsqrtf(vv.w + EPSBN) * gv.w + bv.w, 0.f);
    *(float4*)(OUT + (size_t)dst * THL + base) = o;
}

// ---------------- MFMA 2-layer GRU: R23 = skew + reg-h + parity dbuf (1 barrier/step) ----------------
// fp32 h state lives in REGISTERS (each (node,jr) owned by exactly one thread);
// bf16 h (MFMA A-operand, cross-lane) double-buffered by step parity:
//   L0 writes hb0[t&1], reads hb0[(t-1)&1]; L1 writes hb1[(t-1)&1], reads hb1[t&1]
// -> within-step reads/writes hit different slots -> single end-of-step barrier.
__global__ __launch_bounds__(256, 1) void k_gruM(const float* __restrict__ IN,
                                                 const float* __restrict__ wih0, const float* __restrict__ whh0,
                                                 const float* __restrict__ bih0, const float* __restrict__ bhh0,
                                                 const float* __restrict__ wih1, const float* __restrict__ whh1,
                                                 const float* __restrict__ bih1, const float* __restrict__ bhh1,
                                                 float* __restrict__ hout) {
    __shared__ unsigned short hb0[2][NB][72];
    __shared__ unsigned short hb1[2][NB][72];
    int tid = threadIdx.x;
    int w = tid >> 6, lane = tid & 63;
    int l15 = lane & 15, l4 = lane >> 4;
    int nb0 = blockIdx.x * NB;
    short8v bw[4][3][2];
    const float* Wm[4] = { wih0, whh0, wih1, whh1 };
#pragma unroll
    for (int m = 0; m < 4; ++m)
#pragma unroll
        for (int g = 0; g < 3; ++g)
#pragma unroll
            for (int kk = 0; kk < 2; ++kk) {
                const float* src = Wm[m] + (size_t)(64 * g + 16 * w + l15) * HH + kk * 32 + l4 * 8;
                float4 v0 = *(const float4*)src;
                float4 v1 = *(const float4*)(src + 4);
                short8v f;
                f[0] = (short)f2bf(v0.x); f[1] = (short)f2bf(v0.y);
                f[2] = (short)f2bf(v0.z); f[3] = (short)f2bf(v0.w);
                f[4] = (short)f2bf(v1.x); f[5] = (short)f2bf(v1.y);
                f[6] = (short)f2bf(v1.z); f[7] = (short)f2bf(v1.w);
                bw[m][g][kk] = f;
            }
    int jr = 16 * w + l15;
    float b0r = bih0[jr] + bhh0[jr];
    float b0z = bih0[64 + jr] + bhh0[64 + jr];
    float b0n = bih0[128 + jr];
    float h0n = bhh0[128 + jr];
    float b1r = bih1[jr] + bhh1[jr];
    float b1z = bih1[64 + jr] + bhh1[64 + jr];
    float b1n = bih1[128 + jr];
    float h1n = bhh1[128 + jr];
    // fp32 h state in registers: rh0[i]/rh1[i] for node = l4*4+i, col jr
    float rh0[4] = {0.f, 0.f, 0.f, 0.f};
    float rh1[4] = {0.f, 0.f, 0.f, 0.f};
    for (int i = tid; i < 2 * NB * 72; i += 256) {
        ((unsigned short*)hb0)[i] = 0;
        ((unsigned short*)hb1)[i] = 0;
    }
    __syncthreads();
    const float* xb = IN + (size_t)(nb0 + l15) * (TT * HH);
    // prefetch + convert x(0)
    short8v axn[2];
    {
#pragma unroll
        for (int kk = 0; kk < 2; ++kk) {
            const float* xs = xb + kk * 32 + l4 * 8;
            float4 v0 = *(const float4*)xs;
            float4 v1 = *(const float4*)(xs + 4);
            short8v f;
            f[0] = (short)f2bf(v0.x); f[1] = (short)f2bf(v0.y);
            f[2] = (short)f2bf(v0.z); f[3] = (short)f2bf(v0.w);
            f[4] = (short)f2bf(v1.x); f[5] = (short)f2bf(v1.y);
            f[6] = (short)f2bf(v1.z); f[7] = (short)f2bf(v1.w);
            axn[kk] = f;
        }
    }
#pragma unroll 1
    for (int t = 0; t <= TT; ++t) {
        bool act0 = (t < TT);
        bool act1 = (t >= 1);
        int sw0 = t & 1;          // L0 write slot (h0(t))
        int sr0 = (t - 1) & 1;    // L0/L1 read slot (h0(t-1))
        int sw1 = (t - 1) & 1;    // L1 write slot (h1(t-1))
        int sr1 = t & 1;          // L1 read slot (h1(t-2))
        short8v ax[2], ah0[2], ah1[2];
#pragma unroll
        for (int kk = 0; kk < 2; ++kk) {
            ax[kk] = axn[kk];
            ah0[kk] = *(const short8v*)&hb0[sr0][l15][kk * 32 + l4 * 8];
            ah1[kk] = *(const short8v*)&hb1[sr1][l15][kk * 32 + l4 * 8];
        }
        // prefetch + convert x(t+1) in compute shadow
        if (t + 1 < TT) {
#pragma unroll
            for (int kk = 0; kk < 2; ++kk) {
                const float* xs = xb + (size_t)(t + 1) * HH + kk * 32 + l4 * 8;
                float4 v0 = *(const float4*)xs;
                float4 v1 = *(const float4*)(xs + 4);
                short8v f;
                f[0] = (short)f2bf(v0.x); f[1] = (short)f2bf(v0.y);
                f[2] = (short)f2bf(v0.z); f[3] = (short)f2bf(v0.w);
                f[4] = (short)f2bf(v1.x); f[5] = (short)f2bf(v1.y);
                f[6] = (short)f2bf(v1.z); f[7] = (short)f2bf(v1.w);
                axn[kk] = f;
            }
        }
        if (act0) {
            f32x4 gr = { b0r, b0r, b0r, b0r };
            f32x4 gz = { b0z, b0z, b0z, b0z };
            f32x4 gn = { b0n, b0n, b0n, b0n };
            f32x4 hr = { 0.f, 0.f, 0.f, 0.f };
            f32x4 hz = { 0.f, 0.f, 0.f, 0.f };
            f32x4 hn = { h0n, h0n, h0n, h0n };
#pragma unroll
            for (int kk = 0; kk < 2; ++kk) {
                gr = __builtin_amdgcn_mfma_f32_16x16x32_bf16(ax[kk], bw[0][0][kk], gr, 0, 0, 0);
                gz = __builtin_amdgcn_mfma_f32_16x16x32_bf16(ax[kk], bw[0][1][kk], gz, 0, 0, 0);
                gn = __builtin_amdgcn_mfma_f32_16x16x32_bf16(ax[kk], bw[0][2][kk], gn, 0, 0, 0);
                hr = __builtin_amdgcn_mfma_f32_16x16x32_bf16(ah0[kk], bw[1][0][kk], hr, 0, 0, 0);
                hz = __builtin_amdgcn_mfma_f32_16x16x32_bf16(ah0[kk], bw[1][1][kk], hz, 0, 0, 0);
                hn = __builtin_amdgcn_mfma_f32_16x16x32_bf16(ah0[kk], bw[1][2][kk], hn, 0, 0, 0);
            }
#pragma unroll
            for (int i = 0; i < 4; ++i) {
                int node = l4 * 4 + i;
                float r = fsigmoid(gr[i] + hr[i]);
                float z = fsigmoid(gz[i] + hz[i]);
                float nn2 = ftanh(gn[i] + r * hn[i]);
                float hv = (1.f - z) * nn2 + z * rh0[i];
                rh0[i] = hv;
                hb0[sw0][node][jr] = f2bf(hv);
            }
        }
        if (act1) {
            f32x4 gr = { b1r, b1r, b1r, b1r };
            f32x4 gz = { b1z, b1z, b1z, b1z };
            f32x4 gn = { b1n, b1n, b1n, b1n };
            f32x4 hr = { 0.f, 0.f, 0.f, 0.f };
            f32x4 hz = { 0.f, 0.f, 0.f, 0.f };
            f32x4 hn = { h1n, h1n, h1n, h1n };
#pragma unroll
            for (int kk = 0; kk < 2; ++kk) {
                gr = __builtin_amdgcn_mfma_f32_16x16x32_bf16(ah0[kk], bw[2][0][kk], gr, 0, 0, 0);
                gz = __builtin_amdgcn_mfma_f32_16x16x32_bf16(ah0[kk], bw[2][1][kk], gz, 0, 0, 0);
                gn = __builtin_amdgcn_mfma_f32_16x16x32_bf16(ah0[kk], bw[2][2][kk], gn, 0, 0, 0);
                hr = __builtin_amdgcn_mfma_f32_16x16x32_bf16(ah1[kk], bw[3][0][kk], hr, 0, 0, 0);
                hz = __builtin_amdgcn_mfma_f32_16x16x32_bf16(ah1[kk], bw[3][1][kk], hz, 0, 0, 0);
                hn = __builtin_amdgcn_mfma_f32_16x16x32_bf16(ah1[kk], bw[3][2][kk], hn, 0, 0, 0);
            }
#pragma unroll
            for (int i = 0; i < 4; ++i) {
                int node = l4 * 4 + i;
                float r = fsigmoid(gr[i] + hr[i]);
                float z = fsigmoid(gz[i] + hz[i]);
                float nn2 = ftanh(gn[i] + r * hn[i]);
                float hv = (1.f - z) * nn2 + z * rh1[i];
                rh1[i] = hv;
                hb1[sw1][node][jr] = f2bf(hv);
            }
        }
        __syncthreads();   // single barrier: this step's writes visible to next step's reads
    }
    // write final h1 from registers: thread owns (node = l4*4+i, col jr)
#pragma unroll
    for (int i = 0; i < 4; ++i) {
        int node = l4 * 4 + i;
        hout[(size_t)(nb0 + node) * HH + jr] = rh1[i];
    }
}

// ---------------- head: BN + relu + linear + log_softmax ----------------
__global__ __launch_bounds__(256) void k_head(const float* __restrict__ Hf,
                                              const float* __restrict__ g, const float* __restrict__ b,
                                              const float* __restrict__ m, const float* __restrict__ v,
                                              const float* __restrict__ W, const float* __restrict__ wb,
                                              float* __restrict__ out) {
    __shared__ float hb[4][HH];
    __shared__ float lg[4][CC];
    int tid = threadIdx.x;
    int n0 = blockIdx.x * 4;
    int wv = tid >> 6, lane = tid & 63;
    int n = n0 + wv;
    float x = Hf[(size_t)n * HH + lane];
    x = (x - m[lane]) * rsqrtf(v[lane] + EPSBN) * g[lane] + b[lane];
    hb[wv][lane] = fmaxf(x, 0.f);
    __syncthreads();
    if (tid < 4 * CC) {
        int nn = tid / CC, c = tid % CC;
        float acc = wb[c];
        for (int f = 0; f < HH; ++f) acc += hb[nn][f] * W[c * HH + f];
        lg[nn][c] = acc;
    }
    __syncthreads();
    if (tid < 4 * CC) {
        int nn = tid / CC, c = tid % CC;
        float mx = -1e30f;
#pragma unroll
        for (int i = 0; i < CC; ++i) mx = fmaxf(mx, lg[nn][i]);
        float s = 0.f;
#pragma unroll
        for (int i = 0; i < CC; ++i) s += __expf(lg[nn][i] - mx);
        out[(size_t)(n0 + nn) * CC + c] = lg[nn][c] - mx - __logf(s);
    }
}

// ---------------- launch ----------------
extern "C" void kernel_launch(void* const* d_in, const int* in_sizes, int n_in,
                              void* d_out, int out_size, void* d_ws, size_t ws_size,
                              hipStream_t stream) {
    const float* x_seq     = (const float*)d_in[0];
    const int*   edge_idx  = (const int*)d_in[1];
    const float* edge_w    = (const float*)d_in[2];
    const float* causal_w  = (const float*)d_in[3];
    const float* lin_in_w  = (const float*)d_in[4];
    const float* lin_in_b  = (const float*)d_in[5];
    const float* fusion_w  = (const float*)d_in[6];
    const float* fusion_b  = (const float*)d_in[7];
    const float* gcn_w0    = (const float*)d_in[8];
    const float* gcn_b0    = (const float*)d_in[9];
    const float* gcn_w1    = (const float*)d_in[10];
    const float* gcn_b1    = (const float*)d_in[11];
    const float* bn0_g = (const float*)d_in[12], *bn0_b = (const float*)d_in[13];
    const float* bn0_m = (const float*)d_in[14], *bn0_v = (const float*)d_in[15];
    const float* bn1_g = (const float*)d_in[16], *bn1_b = (const float*)d_in[17];
    const float* bn1_m = (const float*)d_in[18], *bn1_v = (const float*)d_in[19];
    const float* wih0 = (const float*)d_in[20], *whh0 = (const float*)d_in[21];
    const float* bih0 = (const float*)d_in[22], *bhh0 = (const float*)d_in[23];
    const float* wih1 = (const float*)d_in[24], *whh1 = (const float*)d_in[25];
    const float* bih1 = (const float*)d_in[26], *bhh1 = (const float*)d_in[27];
    const float* bno_g = (const float*)d_in[28], *bno_b = (const float*)d_in[29];
    const float* bno_m = (const float*)d_in[30], *bno_v = (const float*)d_in[31];
    const float* lout_w = (const float*)d_in[32], *lout_b = (const float*)d_in[33];
    float* out = (float*)d_out;

    float* wsf = (float*)d_ws;
    unsigned short* WCH = (unsigned short*)(wsf + OFF_WC);
    float* XA  = wsf + OFF_XA;
    float* XB  = wsf + OFF_XB;
    float* XC  = wsf + OFF_XC;
    unsigned short* XAT = (unsigned short*)(wsf + OFF_XC);
    unsigned short* XBH = (unsigned short*)(wsf + OFF_XB);   // bf16: x_agg (gemm C), then xw output
    float* DEG = wsf + OFF_DEG;
    int* CNT   = (int*)(wsf + OFF_CNT);
    int* CUR   = (int*)(wsf + OFF_CUR);
    int* OFFP  = (int*)(wsf + OFF_OFF);
    int* CSRS  = (int*)(wsf + OFF_CSRS);
    float* CSRN = wsf + OFF_CSRN;
    float* HST  = wsf + OFF_HST;

    // CSR + degree build
    k_zero<<<8, 256, 0, stream>>>(CNT, CUR, DEG);
    k_count<<<(ETOT + 255) / 256, 256, 0, stream>>>(edge_idx, edge_w, CNT, DEG);
    k_scan<<<1, 1024, 0, stream>>>(CNT, OFFP);
    k_fill<<<(ETOT + 255) / 256, 256, 0, stream>>>(edge_idx, edge_w, DEG, OFFP, CUR, CSRS, CSRN);

    hipMemsetAsync(WCH, 0, (size_t)2048 * 2048 * 2, stream);
    k_softmax<<<NN, 256, 0, stream>>>(causal_w, WCH);
    // lin_in -> XA [N,T,H] fp32
    k_lin2<<<NN, 256, 0, stream>>>(x_seq, lin_in_w, lin_in_b, XA);
    // transpose+cast: XA -> XAh_t bf16 [4096][2048]
    dim3 tg(THL / 64, 2048 / 64);
    k_tr<<<tg, 256, 0, stream>>>(XA, XAT);
    // x_agg = WCh @ X (MFMA bf16) -> XBH (bf16)
    dim3 gg(THL / 128, 2048 / 128);
    k_gemm_bf<<<gg, 256, 0, stream>>>(WCH, XAT, XBH);
    // fusion -> XC  (X fp32 + XAgg bf16)
    k_fus2<<<NN, 256, 0, stream>>>(XA, XBH, fusion_w, fusion_b, XC);
    // GCN layer 0: XC -> XBH (xw, bf16) -> XA (agg+bn+relu, fp32)
    k_xw2<<<NN, 256, 0, stream>>>(XC, gcn_w0, XBH);
    dim3 ag(NN, 4);
    k_agg<<<ag, 256, 0, stream>>>(XBH, OFFP, CSRS, CSRN, gcn_b0, bn0_g, bn0_b, bn0_m, bn0_v, XA);
    // GCN layer 1: XA -> XBH -> XC
    k_xw2<<<NN, 256, 0, stream>>>(XA, gcn_w1, XBH);
    k_agg<<<ag, 256, 0, stream>>>(XBH, OFFP, CSRS, CSRN, gcn_b1, bn1_g, bn1_b, bn1_m, bn1_v, XC);

    // MFMA 2-layer GRU (skew + reg-h + parity dbuf): XC -> final h in HST (125 blocks)
    k_gruM<<<NN / NB, 256, 0, stream>>>(XC, wih0, whh0, bih0, bhh0,
                                        wih1, whh1, bih1, bhh1, HST);

    // head
    k_head<<<NN / 4, 256, 0, stream>>>(HST, bno_g, bno_b, bno_m, bno_v, lout_w, lout_b, out);
}

// Round 24
// 361.789 us; speedup vs baseline: 1.0786x; 1.0786x over previous
//
#include <hip/hip_runtime.h>
#include <hip/hip_bf16.h>
#include <math.h>

#define TT 64
#define NN 2000
#define FIN 32
#define HH 64
#define CC 10
#define EE 32000
#define ETOT 34000   // E + N self loops
#define THL 4096     // T*H
#define EPSBN 1e-5f
#define NB 16        // nodes per GRU block

// ---------------- workspace layout (float offsets) ----------------
#define OFF_WC   0u          // WCh bf16 [2048][2048]
#define OFF_XA   4000000u    // 8,192,000  [N,T,H] fp32
#define OFF_XB   12192000u   // 8,192,000  (x_agg bf16 C; then xw bf16 scratch)
#define OFF_XC   20384000u   // 8,192,000  (first: XAh_t bf16 [4096][2048]; then fusion out fp32)
#define OFF_DEG  28576000u   // 2048
#define OFF_H1   28578048u   // 128,000 (unused)
#define OFF_CNT  28706048u   // int 2048
#define OFF_CUR  28708096u   // int 2048
#define OFF_OFF  28710144u   // int 2064
#define OFF_CSRS 28712208u   // int 34016
#define OFF_CSRN 28746224u   // float 34016
#define OFF_HST  28780240u   // float 128,000  (GRU h-state)

typedef __attribute__((ext_vector_type(8))) short short8v;
typedef __attribute__((ext_vector_type(4))) float f32x4;

__device__ __forceinline__ float fsigmoid(float x) { return 1.f / (1.f + __expf(-x)); }
__device__ __forceinline__ float ftanh(float x) {
    float e = __expf(2.f * x);
    return (e - 1.f) / (e + 1.f);
}
__device__ __forceinline__ unsigned short f2bf(float f) {
    __hip_bfloat16 h = __float2bfloat16(f);
    return *reinterpret_cast<unsigned short*>(&h);
}
__device__ __forceinline__ float bf2f(unsigned short u) {
    unsigned int x = ((unsigned int)u) << 16;
    return __int_as_float(x);
}
// async global->LDS, 16B per lane; LDS dest = wave-uniform base + lane*16 (linear)
__device__ __forceinline__ void gload_lds16(const unsigned short* g, unsigned short* l) {
    __builtin_amdgcn_global_load_lds(
        (const __attribute__((address_space(1))) unsigned int*)g,
        (__attribute__((address_space(3))) unsigned int*)l,
        16, 0, 0);
}

// ---------------- CSR build ----------------
__global__ void k_zero(int* cnt, int* cur, float* deg) {
    int i = blockIdx.x * 256 + threadIdx.x;
    if (i < 2048) { cnt[i] = 0; cur[i] = 0; deg[i] = 0.f; }
}

__global__ void k_count(const int* __restrict__ ei, const float* __restrict__ ew,
                        int* cnt, float* deg) {
    int e = blockIdx.x * 256 + threadIdx.x;
    if (e < ETOT) {
        int dst; float w;
        if (e < EE) { dst = ei[EE + e]; w = ew[e]; }
        else        { dst = e - EE;     w = 1.f; }
        atomicAdd(&cnt[dst], 1);
        atomicAdd(&deg[dst], w);
    }
}

__global__ __launch_bounds__(1024) void k_scan(const int* __restrict__ cnt, int* off) {
    __shared__ int s[2048];
    int tid = threadIdx.x;
    s[tid]        = (tid        < NN) ? cnt[tid]        : 0;
    s[tid + 1024] = (tid + 1024 < NN) ? cnt[tid + 1024] : 0;
    __syncthreads();
    for (int d = 1; d < 2048; d <<= 1) {
        int idx = (tid + 1) * (d << 1) - 1;
        if (idx < 2048) s[idx] += s[idx - d];
        __syncthreads();
    }
    if (tid == 0) s[2047] = 0;
    __syncthreads();
    for (int d = 1024; d >= 1; d >>= 1) {
        int idx = (tid + 1) * (d << 1) - 1;
        if (idx < 2048) { int t = s[idx - d]; s[idx - d] = s[idx]; s[idx] += t; }
        __syncthreads();
    }
    off[tid] = s[tid];
    off[tid + 1024] = s[tid + 1024];
}

__global__ void k_fill(const int* __restrict__ ei, const float* __restrict__ ew,
                       const float* __restrict__ deg, const int* __restrict__ off,
                       int* cur, int* csr_src, float* csr_nrm) {
    int e = blockIdx.x * 256 + threadIdx.x;
    if (e < ETOT) {
        int src, dst; float w;
        if (e < EE) { src = ei[e]; dst = ei[EE + e]; w = ew[e]; }
        else        { src = dst = e - EE;            w = 1.f; }
        float ds = rsqrtf(fmaxf(deg[src], 1e-12f));
        float dd = rsqrtf(fmaxf(deg[dst], 1e-12f));
        int pos = off[dst] + atomicAdd(&cur[dst], 1);
        csr_src[pos] = src;
        csr_nrm[pos] = ds * w * dd;
    }
}

// ---------------- softmax over causal_weight rows -> bf16 WCh [2048 stride] ----------------
__global__ __launch_bounds__(256) void k_softmax(const float* __restrict__ CW,
                                                 unsigned short* __restrict__ WCH) {
    __shared__ float row[NN];
    __shared__ float red[256];
    int r = blockIdx.x, tid = threadIdx.x;
    const float* in = CW + (size_t)r * NN;
    float mx = -1e30f;
    for (int i = tid; i < NN; i += 256) { float v = in[i]; row[i] = v; mx = fmaxf(mx, v); }
    red[tid] = mx; __syncthreads();
    for (int s = 128; s > 0; s >>= 1) {
        if (tid < s) red[tid] = fmaxf(red[tid], red[tid + s]);
        __syncthreads();
    }
    mx = red[0]; __syncthreads();
    float sm = 0.f;
    for (int i = tid; i < NN; i += 256) { float e = __expf(row[i] - mx); row[i] = e; sm += e; }
    red[tid] = sm; __syncthreads();
    for (int s = 128; s > 0; s >>= 1) {
        if (tid < s) red[tid] += red[tid + s];
        __syncthreads();
    }
    float inv = 1.f / red[0];
    unsigned short* out = WCH + (size_t)r * 2048;
    for (int i = tid; i < 2048; i += 256)
        out[i] = (i < NN) ? f2bf(row[i] * inv) : (unsigned short)0;
}

// ---------------- lin_in as tiled GEMM: rows=(n,t), K=32, 64 cols ----------------
__global__ __launch_bounds__(256) void k_lin2(const float* __restrict__ XS,
                                              const float* __restrict__ W,
                                              const float* __restrict__ b,
                                              float* __restrict__ OUT) {
    __shared__ float Wt[FIN][68];   // [k][o]
    __shared__ float As[FIN][68];   // [k][row]
    int tid = threadIdx.x;
    int n = blockIdx.x;
    for (int i = tid; i < HH * FIN; i += 256) { int o = i >> 5, k = i & 31; Wt[k][o] = W[i]; }
    int row = tid >> 2, kq = tid & 3;   // row = t
    {
        const float4* src = (const float4*)(XS + ((size_t)row * NN + n) * FIN + kq * 8);
        float4 v0 = src[0], v1 = src[1];
        As[kq * 8 + 0][row] = v0.x; As[kq * 8 + 1][row] = v0.y;
        As[kq * 8 + 2][row] = v0.z; As[kq * 8 + 3][row] = v0.w;
        As[kq * 8 + 4][row] = v1.x; As[kq * 8 + 5][row] = v1.y;
        As[kq * 8 + 6][row] = v1.z; As[kq * 8 + 7][row] = v1.w;
    }
    __syncthreads();
    int tx = tid & 15, ty = tid >> 4;
    float acc[4][4] = {};
#pragma unroll
    for (int k = 0; k < FIN; ++k) {
        float4 av = *(const float4*)&As[k][ty * 4];
        float4 wv = *(const float4*)&Wt[k][tx * 4];
        acc[0][0] += av.x * wv.x; acc[0][1] += av.x * wv.y; acc[0][2] += av.x * wv.z; acc[0][3] += av.x * wv.w;
        acc[1][0] += av.y * wv.x; acc[1][1] += av.y * wv.y; acc[1][2] += av.y * wv.z; acc[1][3] += av.y * wv.w;
        acc[2][0] += av.z * wv.x; acc[2][1] += av.z * wv.y; acc[2][2] += av.z * wv.z; acc[2][3] += av.z * wv.w;
        acc[3][0] += av.w * wv.x; acc[3][1] += av.w * wv.y; acc[3][2] += av.w * wv.z; acc[3][3] += av.w * wv.w;
    }
    float4 bv = *(const float4*)(b + tx * 4);
#pragma unroll
    for (int ii = 0; ii < 4; ++ii) {
        float4 o;
        o.x = fmaxf(acc[ii][0] + bv.x, 0.f);
        o.y = fmaxf(acc[ii][1] + bv.y, 0.f);
        o.z = fmaxf(acc[ii][2] + bv.z, 0.f);
        o.w = fmaxf(acc[ii][3] + bv.w, 0.f);
        *(float4*)(OUT + ((size_t)n * TT + ty * 4 + ii) * HH + tx * 4) = o;
    }
}

// ---------------- transpose + bf16 cast ----------------
__global__ __launch_bounds__(256) void k_tr(const float* __restrict__ X,
                                            unsigned short* __restrict__ XT) {
    __shared__ unsigned short tile[64][65];
    int cb = blockIdx.x * 64;
    int kb = blockIdx.y * 64;
    int tid = threadIdx.x;
    int r = tid >> 2, cq = tid & 3;
    const float4* src = (const float4*)(X + (size_t)(kb + r) * THL + cb + cq * 16);
#pragma unroll
    for (int j = 0; j < 4; ++j) {
        float4 v = src[j];
        tile[cq * 16 + j * 4 + 0][r] = f2bf(v.x);
        tile[cq * 16 + j * 4 + 1][r] = f2bf(v.y);
        tile[cq * 16 + j * 4 + 2][r] = f2bf(v.z);
        tile[cq * 16 + j * 4 + 3][r] = f2bf(v.w);
    }
    __syncthreads();
    int cl = tid >> 2, kq = tid & 3;
    unsigned short tmp[16];
#pragma unroll
    for (int j = 0; j < 16; ++j) tmp[j] = tile[cl][kq * 16 + j];
    unsigned short* dst = XT + (size_t)(cb + cl) * 2048 + kb + kq * 16;
    *(uint4*)dst = *(uint4*)tmp;
    *(uint4*)(dst + 8) = *(uint4*)(tmp + 8);
}

// ---------------- bf16 MFMA GEMM: C(bf16)[2000,4096] = WCh @ X (via XAh_t) — R22 proven ----------------
__global__ __launch_bounds__(256, 1) void k_gemm_bf(const unsigned short* __restrict__ A,
                                                    const unsigned short* __restrict__ B,
                                                    unsigned short* __restrict__ CH) {
    __shared__ unsigned short As[128][64];   // 16 KB, linear
    __shared__ unsigned short Bs[128][64];
    int tid = threadIdx.x;
    int mb = blockIdx.y * 128, nb = blockIdx.x * 128;
    int w = tid >> 6, lane = tid & 63;
    int wr = w >> 1, wc = w & 1;
    int l15 = lane & 15, l4 = lane >> 4;
    f32x4 acc[4][4] = {};
    int r_base = w * 8 + (lane >> 3);
    int colu = (lane & 7) * 8;
    for (int kt = 0; kt < 32; ++kt) {
        __syncthreads();
#pragma unroll
        for (int c = 0; c < 4; ++c) {
            int row = c * 32 + r_base;
            gload_lds16(A + (size_t)(mb + row) * 2048 + kt * 64 + colu, &As[c * 32 + w * 8][0]);
            gload_lds16(B + (size_t)(nb + row) * 2048 + kt * 64 + colu, &Bs[c * 32 + w * 8][0]);
        }
        __syncthreads();
#pragma unroll
        for (int kk = 0; kk < 2; ++kk) {
            short8v af[4], bfr[4];
#pragma unroll
            for (int f = 0; f < 4; ++f) {
                af[f]  = *(const short8v*)&As[wr * 64 + f * 16 + l15][kk * 32 + l4 * 8];
                bfr[f] = *(const short8v*)&Bs[wc * 64 + f * 16 + l15][kk * 32 + l4 * 8];
            }
#pragma unroll
            for (int fm = 0; fm < 4; ++fm)
#pragma unroll
                for (int fn = 0; fn < 4; ++fn)
                    acc[fm][fn] = __builtin_amdgcn_mfma_f32_16x16x32_bf16(af[fm], bfr[fn], acc[fm][fn], 0, 0, 0);
        }
    }
    unsigned short* epi = (unsigned short*)(&As[0][0]) + (size_t)w * (16 * 72);
    int erow8 = lane >> 3;
    int ecol8 = lane & 7;
#pragma unroll
    for (int fm = 0; fm < 4; ++fm) {
        __syncthreads();
#pragma unroll
        for (int fn = 0; fn < 4; ++fn)
#pragma unroll
            for (int rr = 0; rr < 4; ++rr)
                epi[(l4 * 4 + rr) * 72 + fn * 16 + l15] = f2bf(acc[fm][fn][rr]);
        __syncthreads();
#pragma unroll
        for (int rh = 0; rh < 2; ++rh) {
            int lrow = rh * 8 + erow8;
            int grow = mb + wr * 64 + fm * 16 + lrow;
            if (grow < NN) {
                *(uint4*)(CH + (size_t)grow * THL + nb + wc * 64 + ecol8 * 8)
                    = *(const uint4*)&epi[lrow * 72 + ecol8 * 8];
            }
        }
    }
}

// ---------------- fusion as tiled GEMM: K=128 (X fp32 + XAgg bf16), 64 cols ----------------
__global__ __launch_bounds__(256) void k_fus2(const float* __restrict__ X,
                                              const unsigned short* __restrict__ XAH,
                                              const float* __restrict__ W,
                                              const float* __restrict__ b,
                                              float* __restrict__ OUT) {
    __shared__ float Wt[2 * HH][68];
    __shared__ float As[HH][68];
    int tid = threadIdx.x;
    size_t r0 = (size_t)blockIdx.x * 64;
    for (int i = tid; i < HH * 2 * HH; i += 256) { int o = i >> 7, k = i & 127; Wt[k][o] = W[i]; }
    int row = tid >> 2, kq = tid & 3;
    int tx = tid & 15, ty = tid >> 4;
    float acc[4][4] = {};
    __syncthreads();
    {
        const float4* src = (const float4*)(X + (r0 + row) * HH + kq * 16);
#pragma unroll
        for (int j = 0; j < 4; ++j) {
            float4 v = src[j];
            As[kq * 16 + j * 4 + 0][row] = v.x;
            As[kq * 16 + j * 4 + 1][row] = v.y;
            As[kq * 16 + j * 4 + 2][row] = v.z;
            As[kq * 16 + j * 4 + 3][row] = v.w;
        }
    }
    __syncthreads();
#pragma unroll
    for (int k = 0; k < HH; ++k) {
        float4 av = *(const float4*)&As[k][ty * 4];
        float4 wv = *(const float4*)&Wt[k][tx * 4];
        acc[0][0] += av.x * wv.x; acc[0][1] += av.x * wv.y; acc[0][2] += av.x * wv.z; acc[0][3] += av.x * wv.w;
        acc[1][0] += av.y * wv.x; acc[1][1] += av.y * wv.y; acc[1][2] += av.y * wv.z; acc[1][3] += av.y * wv.w;
        acc[2][0] += av.z * wv.x; acc[2][1] += av.z * wv.y; acc[2][2] += av.z * wv.z; acc[2][3] += av.z * wv.w;
        acc[3][0] += av.w * wv.x; acc[3][1] += av.w * wv.y; acc[3][2] += av.w * wv.z; acc[3][3] += av.w * wv.w;
    }
    __syncthreads();
    {
        const uint4* s = (const uint4*)(XAH + (r0 + row) * HH + kq * 16);
        uint4 u0 = s[0], u1 = s[1];
        unsigned short us[16];
        *(uint4*)us = u0; *(uint4*)(us + 8) = u1;
#pragma unroll
        for (int j = 0; j < 16; ++j)
            As[kq * 16 + j][row] = bf2f(us[j]);
    }
    __syncthreads();
#pragma unroll
    for (int k = 0; k < HH; ++k) {
        float4 av = *(const float4*)&As[k][ty * 4];
        float4 wv = *(const float4*)&Wt[HH + k][tx * 4];
        acc[0][0] += av.x * wv.x; acc[0][1] += av.x * wv.y; acc[0][2] += av.x * wv.z; acc[0][3] += av.x * wv.w;
        acc[1][0] += av.y * wv.x; acc[1][1] += av.y * wv.y; acc[1][2] += av.y * wv.z; acc[1][3] += av.y * wv.w;
        acc[2][0] += av.z * wv.x; acc[2][1] += av.z * wv.y; acc[2][2] += av.z * wv.z; acc[2][3] += av.z * wv.w;
        acc[3][0] += av.w * wv.x; acc[3][1] += av.w * wv.y; acc[3][2] += av.w * wv.z; acc[3][3] += av.w * wv.w;
    }
    float4 bv = *(const float4*)(b + tx * 4);
#pragma unroll
    for (int ii = 0; ii < 4; ++ii) {
        float4 o;
        o.x = fmaxf(acc[ii][0] + bv.x, 0.f);
        o.y = fmaxf(acc[ii][1] + bv.y, 0.f);
        o.z = fmaxf(acc[ii][2] + bv.z, 0.f);
        o.w = fmaxf(acc[ii][3] + bv.w, 0.f);
        *(float4*)(OUT + (r0 + ty * 4 + ii) * HH + tx * 4) = o;
    }
}

// ---------------- GCN xw as tiled GEMM: K=64, 64 cols, bf16 output ----------------
__global__ __launch_bounds__(256) void k_xw2(const float* __restrict__ IN,
                                             const float* __restrict__ W,
                                             unsigned short* __restrict__ OUT) {
    __shared__ float Wt[HH][68];
    __shared__ float As[HH][68];
    int tid = threadIdx.x;
    size_t r0 = (size_t)blockIdx.x * 64;
    for (int i = tid; i < HH * HH; i += 256) { int o = i >> 6, k = i & 63; Wt[k][o] = W[i]; }
    int row = tid >> 2, kq = tid & 3;
    {
        const float4* src = (const float4*)(IN + (r0 + row) * HH + kq * 16);
#pragma unroll
        for (int j = 0; j < 4; ++j) {
            float4 v = src[j];
            As[kq * 16 + j * 4 + 0][row] = v.x;
            As[kq * 16 + j * 4 + 1][row] = v.y;
            As[kq * 16 + j * 4 + 2][row] = v.z;
            As[kq * 16 + j * 4 + 3][row] = v.w;
        }
    }
    __syncthreads();
    int tx = tid & 15, ty = tid >> 4;
    float acc[4][4] = {};
#pragma unroll
    for (int k = 0; k < HH; ++k) {
        float4 av = *(const float4*)&As[k][ty * 4];
        float4 wv = *(const float4*)&Wt[k][tx * 4];
        acc[0][0] += av.x * wv.x; acc[0][1] += av.x * wv.y; acc[0][2] += av.x * wv.z; acc[0][3] += av.x * wv.w;
        acc[1][0] += av.y * wv.x; acc[1][1] += av.y * wv.y; acc[1][2] += av.y * wv.z; acc[1][3] += av.y * wv.w;
        acc[2][0] += av.z * wv.x; acc[2][1] += av.z * wv.y; acc[2][2] += av.z * wv.z; acc[2][3] += av.z * wv.w;
        acc[3][0] += av.w * wv.x; acc[3][1] += av.w * wv.y; acc[3][2] += av.w * wv.z; acc[3][3] += av.w * wv.w;
    }
#pragma unroll
    for (int ii = 0; ii < 4; ++ii) {
        unsigned int p0 = (unsigned int)f2bf(acc[ii][0]) | ((unsigned int)f2bf(acc[ii][1]) << 16);
        unsigned int p1 = (unsigned int)f2bf(acc[ii][2]) | ((unsigned int)f2bf(acc[ii][3]) << 16);
        uint2 pk; pk.x = p0; pk.y = p1;
        *(uint2*)(OUT + (r0 + ty * 4 + ii) * HH + tx * 4) = pk;
    }
}

// ---------------- GCN aggregate (CSR, bf16 in) + bias + BN + relu ----------------
__global__ __launch_bounds__(256) void k_agg(const unsigned short* __restrict__ XW,
                                             const int* __restrict__ off,
                                             const int* __restrict__ csr_src,
                                             const float* __restrict__ csr_nrm,
                                             const float* __restrict__ bias,
                                             const float* __restrict__ g,
                                             const float* __restrict__ bb,
                                             const float* __restrict__ m,
                                             const float* __restrict__ v,
                                             float* __restrict__ OUT) {
    int dst = blockIdx.x, ch = blockIdx.y, tid = threadIdx.x;
    int base = ch * 1024 + tid * 4;
    float4 acc = make_float4(0.f, 0.f, 0.f, 0.f);
    int beg = off[dst], end = off[dst + 1];
    for (int e = beg; e < end; ++e) {
        int src = csr_src[e];
        float w = csr_nrm[e];
        uint2 u = *(const uint2*)(XW + (size_t)src * THL + base);
        acc.x += w * bf2f((unsigned short)(u.x & 0xffff));
        acc.y += w * bf2f((unsigned short)(u.x >> 16));
        acc.z += w * bf2f((unsigned short)(u.y & 0xffff));
        acc.w += w * bf2f((unsigned short)(u.y >> 16));
    }
    int h0 = base & 63;
    float4 bs = *(const float4*)(bias + h0);
    float4 gv = *(const float4*)(g + h0);
    float4 vv = *(const float4*)(v + h0);
    float4 mv = *(const float4*)(m + h0);
    float4 bv = *(const float4*)(bb + h0);
    float4 o;
    o.x = fmaxf((acc.x + bs.x - mv.x) * rsqrtf(vv.x + EPSBN) * gv.x + bv.x, 0.f);
    o.y = fmaxf((acc.y + bs.y - mv.y) * rsqrtf(vv.y + EPSBN) * gv.y + bv.y, 0.f);
    o.z = fmaxf((acc.z + bs.z - mv.z) * rsqrtf(vv.z + EPSBN) * gv.z + bv.z, 0.f);
    o.w = fmaxf((acc.w + bs.w - mv.w) * rsqrtf(vv.w + EPSBN) * gv.w + bv.w, 0.f);
    *(float4*)(OUT + (size_t)dst * THL + base) = o;
}

// ---------------- MFMA 2-layer GRU (R22 best-known): skew + LDS fp32 h + x-prefetch ----------------
__global__ __launch_bounds__(256, 1) void k_gruM(const float* __restrict__ IN,
                                                 const float* __restrict__ wih0, const float* __restrict__ whh0,
                                                 const float* __restrict__ bih0, const float* __restrict__ bhh0,
                                                 const float* __restrict__ wih1, const float* __restrict__ whh1,
                                                 const float* __restrict__ bih1, const float* __restrict__ bhh1,
                                                 float* __restrict__ hout) {
    __shared__ float hf0[NB][68];
    __shared__ float hf1[NB][68];
    __shared__ unsigned short hb0[NB][72];
    __shared__ unsigned short hb1[NB][72];
    int tid = threadIdx.x;
    int w = tid >> 6, lane = tid & 63;
    int l15 = lane & 15, l4 = lane >> 4;
    int nb0 = blockIdx.x * NB;
    short8v bw[4][3][2];
    const float* Wm[4] = { wih0, whh0, wih1, whh1 };
#pragma unroll
    for (int m = 0; m < 4; ++m)
#pragma unroll
        for (int g = 0; g < 3; ++g)
#pragma unroll
            for (int kk = 0; kk < 2; ++kk) {
                const float* src = Wm[m] + (size_t)(64 * g + 16 * w + l15) * HH + kk * 32 + l4 * 8;
                float4 v0 = *(const float4*)src;
                float4 v1 = *(const float4*)(src + 4);
                short8v f;
                f[0] = (short)f2bf(v0.x); f[1] = (short)f2bf(v0.y);
                f[2] = (short)f2bf(v0.z); f[3] = (short)f2bf(v0.w);
                f[4] = (short)f2bf(v1.x); f[5] = (short)f2bf(v1.y);
                f[6] = (short)f2bf(v1.z); f[7] = (short)f2bf(v1.w);
                bw[m][g][kk] = f;
            }
    int jr = 16 * w + l15;
    float b0r = bih0[jr] + bhh0[jr];
    float b0z = bih0[64 + jr] + bhh0[64 + jr];
    float b0n = bih0[128 + jr];
    float h0n = bhh0[128 + jr];
    float b1r = bih1[jr] + bhh1[jr];
    float b1z = bih1[64 + jr] + bhh1[64 + jr];
    float b1n = bih1[128 + jr];
    float h1n = bhh1[128 + jr];
    for (int i = tid; i < NB * 68; i += 256) { ((float*)hf0)[i] = 0.f; ((float*)hf1)[i] = 0.f; }
    for (int i = tid; i < NB * 72; i += 256) { ((unsigned short*)hb0)[i] = 0; ((unsigned short*)hb1)[i] = 0; }
    __syncthreads();
    const float* xb = IN + (size_t)(nb0 + l15) * (TT * HH);
    float4 xv[4];
    {
        const float* xs = xb + 0 * HH + l4 * 8;
        xv[0] = *(const float4*)xs; xv[1] = *(const float4*)(xs + 4);
        const float* xs2 = xb + 0 * HH + 32 + l4 * 8;
        xv[2] = *(const float4*)xs2; xv[3] = *(const float4*)(xs2 + 4);
    }
#pragma unroll 1
    for (int t = 0; t <= TT; ++t) {
        bool act0 = (t < TT);
        bool act1 = (t >= 1);
        short8v ax[2], ah0[2], ah1[2];
#pragma unroll
        for (int kk = 0; kk < 2; ++kk) {
            float4 v0 = xv[kk * 2], v1 = xv[kk * 2 + 1];
            short8v f;
            f[0] = (short)f2bf(v0.x); f[1] = (short)f2bf(v0.y);
            f[2] = (short)f2bf(v0.z); f[3] = (short)f2bf(v0.w);
            f[4] = (short)f2bf(v1.x); f[5] = (short)f2bf(v1.y);
            f[6] = (short)f2bf(v1.z); f[7] = (short)f2bf(v1.w);
            ax[kk] = f;
            ah0[kk] = *(const short8v*)&hb0[l15][kk * 32 + l4 * 8];
            ah1[kk] = *(const short8v*)&hb1[l15][kk * 32 + l4 * 8];
        }
        __syncthreads();
        if (t + 1 < TT) {
            const float* xs = xb + (size_t)(t + 1) * HH + l4 * 8;
            xv[0] = *(const float4*)xs; xv[1] = *(const float4*)(xs + 4);
            const float* xs2 = xb + (size_t)(t + 1) * HH + 32 + l4 * 8;
            xv[2] = *(const float4*)xs2; xv[3] = *(const float4*)(xs2 + 4);
        }
        if (act0) {
            f32x4 gr = { b0r, b0r, b0r, b0r };
            f32x4 gz = { b0z, b0z, b0z, b0z };
            f32x4 gn = { b0n, b0n, b0n, b0n };
            f32x4 hr = { 0.f, 0.f, 0.f, 0.f };
            f32x4 hz = { 0.f, 0.f, 0.f, 0.f };
            f32x4 hn = { h0n, h0n, h0n, h0n };
#pragma unroll
            for (int kk = 0; kk < 2; ++kk) {
                gr = __builtin_amdgcn_mfma_f32_16x16x32_bf16(ax[kk], bw[0][0][kk], gr, 0, 0, 0);
                gz = __builtin_amdgcn_mfma_f32_16x16x32_bf16(ax[kk], bw[0][1][kk], gz, 0, 0, 0);
                gn = __builtin_amdgcn_mfma_f32_16x16x32_bf16(ax[kk], bw[0][2][kk], gn, 0, 0, 0);
                hr = __builtin_amdgcn_mfma_f32_16x16x32_bf16(ah0[kk], bw[1][0][kk], hr, 0, 0, 0);
                hz = __builtin_amdgcn_mfma_f32_16x16x32_bf16(ah0[kk], bw[1][1][kk], hz, 0, 0, 0);
                hn = __builtin_amdgcn_mfma_f32_16x16x32_bf16(ah0[kk], bw[1][2][kk], hn, 0, 0, 0);
            }
#pragma unroll
            for (int i = 0; i < 4; ++i) {
                int node = l4 * 4 + i;
                float r = fsigmoid(gr[i] + hr[i]);
                float z = fsigmoid(gz[i] + hz[i]);
                float nn2 = ftanh(gn[i] + r * hn[i]);
                float ho = hf0[node][jr];
                float hv = (1.f - z) * nn2 + z * ho;
                hf0[node][jr] = hv;
                hb0[node][jr] = f2bf(hv);
            }
        }
        if (act1) {
            f32x4 gr = { b1r, b1r, b1r, b1r };
            f32x4 gz = { b1z, b1z, b1z, b1z };
            f32x4 gn = { b1n, b1n, b1n, b1n };
            f32x4 hr = { 0.f, 0.f, 0.f, 0.f };
            f32x4 hz = { 0.f, 0.f, 0.f, 0.f };
            f32x4 hn = { h1n, h1n, h1n, h1n };
#pragma unroll
            for (int kk = 0; kk < 2; ++kk) {
                gr = __builtin_amdgcn_mfma_f32_16x16x32_bf16(ah0[kk], bw[2][0][kk], gr, 0, 0, 0);
                gz = __builtin_amdgcn_mfma_f32_16x16x32_bf16(ah0[kk], bw[2][1][kk], gz, 0, 0, 0);
                gn = __builtin_amdgcn_mfma_f32_16x16x32_bf16(ah0[kk], bw[2][2][kk], gn, 0, 0, 0);
                hr = __builtin_amdgcn_mfma_f32_16x16x32_bf16(ah1[kk], bw[3][0][kk], hr, 0, 0, 0);
                hz = __builtin_amdgcn_mfma_f32_16x16x32_bf16(ah1[kk], bw[3][1][kk], hz, 0, 0, 0);
                hn = __builtin_amdgcn_mfma_f32_16x16x32_bf16(ah1[kk], bw[3][2][kk], hn, 0, 0, 0);
            }
#pragma unroll
            for (int i = 0; i < 4; ++i) {
                int node = l4 * 4 + i;
                float r = fsigmoid(gr[i] + hr[i]);
                float z = fsigmoid(gz[i] + hz[i]);
                float nn2 = ftanh(gn[i] + r * hn[i]);
                float ho = hf1[node][jr];
                float hv = (1.f - z) * nn2 + z * ho;
                hf1[node][jr] = hv;
                hb1[node][jr] = f2bf(hv);
            }
        }
        __syncthreads();
    }
    for (int i = tid; i < NB * HH; i += 256) {
        int node = i >> 6, j = i & 63;
        hout[(size_t)(nb0 + node) * HH + j] = hf1[node][j];
    }
}

// ---------------- head: BN + relu + linear + log_softmax ----------------
__global__ __launch_bounds__(256) void k_head(const float* __restrict__ Hf,
                                              const float* __restrict__ g, const float* __restrict__ b,
                                              const float* __restrict__ m, const float* __restrict__ v,
                                              const float* __restrict__ W, const float* __restrict__ wb,
                                              float* __restrict__ out) {
    __shared__ float hb[4][HH];
    __shared__ float lg[4][CC];
    int tid = threadIdx.x;
    int n0 = blockIdx.x * 4;
    int wv = tid >> 6, lane = tid & 63;
    int n = n0 + wv;
    float x = Hf[(size_t)n * HH + lane];
    x = (x - m[lane]) * rsqrtf(v[lane] + EPSBN) * g[lane] + b[lane];
    hb[wv][lane] = fmaxf(x, 0.f);
    __syncthreads();
    if (tid < 4 * CC) {
        int nn = tid / CC, c = tid % CC;
        float acc = wb[c];
        for (int f = 0; f < HH; ++f) acc += hb[nn][f] * W[c * HH + f];
        lg[nn][c] = acc;
    }
    __syncthreads();
    if (tid < 4 * CC) {
        int nn = tid / CC, c = tid % CC;
        float mx = -1e30f;
#pragma unroll
        for (int i = 0; i < CC; ++i) mx = fmaxf(mx, lg[nn][i]);
        float s = 0.f;
#pragma unroll
        for (int i = 0; i < CC; ++i) s += __expf(lg[nn][i] - mx);
        out[(size_t)(n0 + nn) * CC + c] = lg[nn][c] - mx - __logf(s);
    }
}

// ---------------- launch ----------------
extern "C" void kernel_launch(void* const* d_in, const int* in_sizes, int n_in,
                              void* d_out, int out_size, void* d_ws, size_t ws_size,
                              hipStream_t stream) {
    const float* x_seq     = (const float*)d_in[0];
    const int*   edge_idx  = (const int*)d_in[1];
    const float* edge_w    = (const float*)d_in[2];
    const float* causal_w  = (const float*)d_in[3];
    const float* lin_in_w  = (const float*)d_in[4];
    const float* lin_in_b  = (const float*)d_in[5];
    const float* fusion_w  = (const float*)d_in[6];
    const float* fusion_b  = (const float*)d_in[7];
    const float* gcn_w0    = (const float*)d_in[8];
    const float* gcn_b0    = (const float*)d_in[9];
    const float* gcn_w1    = (const float*)d_in[10];
    const float* gcn_b1    = (const float*)d_in[11];
    const float* bn0_g = (const float*)d_in[12], *bn0_b = (const float*)d_in[13];
    const float* bn0_m = (const float*)d_in[14], *bn0_v = (const float*)d_in[15];
    const float* bn1_g = (const float*)d_in[16], *bn1_b = (const float*)d_in[17];
    const float* bn1_m = (const float*)d_in[18], *bn1_v = (const float*)d_in[19];
    const float* wih0 = (const float*)d_in[20], *whh0 = (const float*)d_in[21];
    const float* bih0 = (const float*)d_in[22], *bhh0 = (const float*)d_in[23];
    const float* wih1 = (const float*)d_in[24], *whh1 = (const float*)d_in[25];
    const float* bih1 = (const float*)d_in[26], *bhh1 = (const float*)d_in[27];
    const float* bno_g = (const float*)d_in[28], *bno_b = (const float*)d_in[29];
    const float* bno_m = (const float*)d_in[30], *bno_v = (const float*)d_in[31];
    const float* lout_w = (const float*)d_in[32], *lout_b = (const float*)d_in[33];
    float* out = (float*)d_out;

    float* wsf = (float*)d_ws;
    unsigned short* WCH = (unsigned short*)(wsf + OFF_WC);
    float* XA  = wsf + OFF_XA;
    float* XB  = wsf + OFF_XB;
    float* XC  = wsf + OFF_XC;
    unsigned short* XAT = (unsigned short*)(wsf + OFF_XC);
    unsigned short* XBH = (unsigned short*)(wsf + OFF_XB);   // bf16: x_agg (gemm C), then xw output
    float* DEG = wsf + OFF_DEG;
    int* CNT   = (int*)(wsf + OFF_CNT);
    int* CUR   = (int*)(wsf + OFF_CUR);
    int* OFFP  = (int*)(wsf + OFF_OFF);
    int* CSRS  = (int*)(wsf + OFF_CSRS);
    float* CSRN = wsf + OFF_CSRN;
    float* HST  = wsf + OFF_HST;

    // CSR + degree build
    k_zero<<<8, 256, 0, stream>>>(CNT, CUR, DEG);
    k_count<<<(ETOT + 255) / 256, 256, 0, stream>>>(edge_idx, edge_w, CNT, DEG);
    k_scan<<<1, 1024, 0, stream>>>(CNT, OFFP);
    k_fill<<<(ETOT + 255) / 256, 256, 0, stream>>>(edge_idx, edge_w, DEG, OFFP, CUR, CSRS, CSRN);

    hipMemsetAsync(WCH, 0, (size_t)2048 * 2048 * 2, stream);
    k_softmax<<<NN, 256, 0, stream>>>(causal_w, WCH);
    // lin_in -> XA [N,T,H] fp32
    k_lin2<<<NN, 256, 0, stream>>>(x_seq, lin_in_w, lin_in_b, XA);
    // transpose+cast: XA -> XAh_t bf16 [4096][2048]
    dim3 tg(THL / 64, 2048 / 64);
    k_tr<<<tg, 256, 0, stream>>>(XA, XAT);
    // x_agg = WCh @ X (MFMA bf16) -> XBH (bf16)
    dim3 gg(THL / 128, 2048 / 128);
    k_gemm_bf<<<gg, 256, 0, stream>>>(WCH, XAT, XBH);
    // fusion -> XC  (X fp32 + XAgg bf16)
    k_fus2<<<NN, 256, 0, stream>>>(XA, XBH, fusion_w, fusion_b, XC);
    // GCN layer 0: XC -> XBH (xw, bf16) -> XA (agg+bn+relu, fp32)
    k_xw2<<<NN, 256, 0, stream>>>(XC, gcn_w0, XBH);
    dim3 ag(NN, 4);
    k_agg<<<ag, 256, 0, stream>>>(XBH, OFFP, CSRS, CSRN, gcn_b0, bn0_g, bn0_b, bn0_m, bn0_v, XA);
    // GCN layer 1: XA -> XBH -> XC
    k_xw2<<<NN, 256, 0, stream>>>(XA, gcn_w1, XBH);
    k_agg<<<ag, 256, 0, stream>>>(XBH, OFFP, CSRS, CSRN, gcn_b1, bn1_g, bn1_b, bn1_m, bn1_v, XC);

    // MFMA 2-layer GRU (R22 best-known): XC -> final h in HST (125 blocks)
    k_gruM<<<NN / NB, 256, 0, stream>>>(XC, wih0, whh0, bih0, bhh0,
                                        wih1, whh1, bih1, bhh1, HST);

    // head
    k_head<<<NN / 4, 256, 0, stream>>>(HST, bno_g, bno_b, bno_m, bno_v, lout_w, lout_b, out);
}

// Round 25
// 359.258 us; speedup vs baseline: 1.0862x; 1.0070x over previous
//
#include <hip/hip_runtime.h>
#include <hip/hip_bf16.h>
#include <math.h>

#define TT 64
#define NN 2000
#define FIN 32
#define HH 64
#define CC 10
#define EE 32000
#define ETOT 34000   // E + N self loops
#define THL 4096     // T*H
#define EPSBN 1e-5f
#define NB 16        // nodes per GRU block

// ---------------- workspace layout (float offsets) ----------------
#define OFF_WC   0u          // WCh bf16 [2048][2048]
#define OFF_XA   4000000u    // 8,192,000  [N,T,H] fp32 (lin_in out); later xw1 bf16
#define OFF_XB   12192000u   // 8,192,000  (x_agg bf16 C; then xw0 bf16, in-place)
#define OFF_XC   20384000u   // 8,192,000  (first: XAh_t bf16; then agg1 out fp32 for GRU)
#define OFF_DEG  28576000u   // 2048
#define OFF_H1   28578048u   // 128,000 (unused)
#define OFF_CNT  28706048u   // int 2048
#define OFF_CUR  28708096u   // int 2048
#define OFF_OFF  28710144u   // int 2064
#define OFF_CSRS 28712208u   // int 34016
#define OFF_CSRN 28746224u   // float 34016
#define OFF_HST  28780240u   // float 128,000  (GRU h-state)

typedef __attribute__((ext_vector_type(8))) short short8v;
typedef __attribute__((ext_vector_type(4))) float f32x4;

__device__ __forceinline__ float fsigmoid(float x) { return 1.f / (1.f + __expf(-x)); }
__device__ __forceinline__ float ftanh(float x) {
    float e = __expf(2.f * x);
    return (e - 1.f) / (e + 1.f);
}
__device__ __forceinline__ unsigned short f2bf(float f) {
    __hip_bfloat16 h = __float2bfloat16(f);
    return *reinterpret_cast<unsigned short*>(&h);
}
__device__ __forceinline__ float bf2f(unsigned short u) {
    unsigned int x = ((unsigned int)u) << 16;
    return __int_as_float(x);
}
// async global->LDS, 16B per lane; LDS dest = wave-uniform base + lane*16 (linear)
__device__ __forceinline__ void gload_lds16(const unsigned short* g, unsigned short* l) {
    __builtin_amdgcn_global_load_lds(
        (const __attribute__((address_space(1))) unsigned int*)g,
        (__attribute__((address_space(3))) unsigned int*)l,
        16, 0, 0);
}

// ---------------- CSR build ----------------
__global__ void k_zero(int* cnt, int* cur, float* deg) {
    int i = blockIdx.x * 256 + threadIdx.x;
    if (i < 2048) { cnt[i] = 0; cur[i] = 0; deg[i] = 0.f; }
}

__global__ void k_count(const int* __restrict__ ei, const float* __restrict__ ew,
                        int* cnt, float* deg) {
    int e = blockIdx.x * 256 + threadIdx.x;
    if (e < ETOT) {
        int dst; float w;
        if (e < EE) { dst = ei[EE + e]; w = ew[e]; }
        else        { dst = e - EE;     w = 1.f; }
        atomicAdd(&cnt[dst], 1);
        atomicAdd(&deg[dst], w);
    }
}

__global__ __launch_bounds__(1024) void k_scan(const int* __restrict__ cnt, int* off) {
    __shared__ int s[2048];
    int tid = threadIdx.x;
    s[tid]        = (tid        < NN) ? cnt[tid]        : 0;
    s[tid + 1024] = (tid + 1024 < NN) ? cnt[tid + 1024] : 0;
    __syncthreads();
    for (int d = 1; d < 2048; d <<= 1) {
        int idx = (tid + 1) * (d << 1) - 1;
        if (idx < 2048) s[idx] += s[idx - d];
        __syncthreads();
    }
    if (tid == 0) s[2047] = 0;
    __syncthreads();
    for (int d = 1024; d >= 1; d >>= 1) {
        int idx = (tid + 1) * (d << 1) - 1;
        if (idx < 2048) { int t = s[idx - d]; s[idx - d] = s[idx]; s[idx] += t; }
        __syncthreads();
    }
    off[tid] = s[tid];
    off[tid + 1024] = s[tid + 1024];
}

__global__ void k_fill(const int* __restrict__ ei, const float* __restrict__ ew,
                       const float* __restrict__ deg, const int* __restrict__ off,
                       int* cur, int* csr_src, float* csr_nrm) {
    int e = blockIdx.x * 256 + threadIdx.x;
    if (e < ETOT) {
        int src, dst; float w;
        if (e < EE) { src = ei[e]; dst = ei[EE + e]; w = ew[e]; }
        else        { src = dst = e - EE;            w = 1.f; }
        float ds = rsqrtf(fmaxf(deg[src], 1e-12f));
        float dd = rsqrtf(fmaxf(deg[dst], 1e-12f));
        int pos = off[dst] + atomicAdd(&cur[dst], 1);
        csr_src[pos] = src;
        csr_nrm[pos] = ds * w * dd;
    }
}

// ---------------- softmax over causal_weight rows -> bf16 WCh [2048 stride] ----------------
__global__ __launch_bounds__(256) void k_softmax(const float* __restrict__ CW,
                                                 unsigned short* __restrict__ WCH) {
    __shared__ float row[NN];
    __shared__ float red[256];
    int r = blockIdx.x, tid = threadIdx.x;
    const float* in = CW + (size_t)r * NN;
    float mx = -1e30f;
    for (int i = tid; i < NN; i += 256) { float v = in[i]; row[i] = v; mx = fmaxf(mx, v); }
    red[tid] = mx; __syncthreads();
    for (int s = 128; s > 0; s >>= 1) {
        if (tid < s) red[tid] = fmaxf(red[tid], red[tid + s]);
        __syncthreads();
    }
    mx = red[0]; __syncthreads();
    float sm = 0.f;
    for (int i = tid; i < NN; i += 256) { float e = __expf(row[i] - mx); row[i] = e; sm += e; }
    red[tid] = sm; __syncthreads();
    for (int s = 128; s > 0; s >>= 1) {
        if (tid < s) red[tid] += red[tid + s];
        __syncthreads();
    }
    float inv = 1.f / red[0];
    unsigned short* out = WCH + (size_t)r * 2048;
    for (int i = tid; i < 2048; i += 256)
        out[i] = (i < NN) ? f2bf(row[i] * inv) : (unsigned short)0;
}

// ---------------- lin_in as tiled GEMM: rows=(n,t), K=32, 64 cols ----------------
__global__ __launch_bounds__(256) void k_lin2(const float* __restrict__ XS,
                                              const float* __restrict__ W,
                                              const float* __restrict__ b,
                                              float* __restrict__ OUT) {
    __shared__ float Wt[FIN][68];   // [k][o]
    __shared__ float As[FIN][68];   // [k][row]
    int tid = threadIdx.x;
    int n = blockIdx.x;
    for (int i = tid; i < HH * FIN; i += 256) { int o = i >> 5, k = i & 31; Wt[k][o] = W[i]; }
    int row = tid >> 2, kq = tid & 3;   // row = t
    {
        const float4* src = (const float4*)(XS + ((size_t)row * NN + n) * FIN + kq * 8);
        float4 v0 = src[0], v1 = src[1];
        As[kq * 8 + 0][row] = v0.x; As[kq * 8 + 1][row] = v0.y;
        As[kq * 8 + 2][row] = v0.z; As[kq * 8 + 3][row] = v0.w;
        As[kq * 8 + 4][row] = v1.x; As[kq * 8 + 5][row] = v1.y;
        As[kq * 8 + 6][row] = v1.z; As[kq * 8 + 7][row] = v1.w;
    }
    __syncthreads();
    int tx = tid & 15, ty = tid >> 4;
    float acc[4][4] = {};
#pragma unroll
    for (int k = 0; k < FIN; ++k) {
        float4 av = *(const float4*)&As[k][ty * 4];
        float4 wv = *(const float4*)&Wt[k][tx * 4];
        acc[0][0] += av.x * wv.x; acc[0][1] += av.x * wv.y; acc[0][2] += av.x * wv.z; acc[0][3] += av.x * wv.w;
        acc[1][0] += av.y * wv.x; acc[1][1] += av.y * wv.y; acc[1][2] += av.y * wv.z; acc[1][3] += av.y * wv.w;
        acc[2][0] += av.z * wv.x; acc[2][1] += av.z * wv.y; acc[2][2] += av.z * wv.z; acc[2][3] += av.z * wv.w;
        acc[3][0] += av.w * wv.x; acc[3][1] += av.w * wv.y; acc[3][2] += av.w * wv.z; acc[3][3] += av.w * wv.w;
    }
    float4 bv = *(const float4*)(b + tx * 4);
#pragma unroll
    for (int ii = 0; ii < 4; ++ii) {
        float4 o;
        o.x = fmaxf(acc[ii][0] + bv.x, 0.f);
        o.y = fmaxf(acc[ii][1] + bv.y, 0.f);
        o.z = fmaxf(acc[ii][2] + bv.z, 0.f);
        o.w = fmaxf(acc[ii][3] + bv.w, 0.f);
        *(float4*)(OUT + ((size_t)n * TT + ty * 4 + ii) * HH + tx * 4) = o;
    }
}

// ---------------- transpose + bf16 cast ----------------
__global__ __launch_bounds__(256) void k_tr(const float* __restrict__ X,
                                            unsigned short* __restrict__ XT) {
    __shared__ unsigned short tile[64][65];
    int cb = blockIdx.x * 64;
    int kb = blockIdx.y * 64;
    int tid = threadIdx.x;
    int r = tid >> 2, cq = tid & 3;
    const float4* src = (const float4*)(X + (size_t)(kb + r) * THL + cb + cq * 16);
#pragma unroll
    for (int j = 0; j < 4; ++j) {
        float4 v = src[j];
        tile[cq * 16 + j * 4 + 0][r] = f2bf(v.x);
        tile[cq * 16 + j * 4 + 1][r] = f2bf(v.y);
        tile[cq * 16 + j * 4 + 2][r] = f2bf(v.z);
        tile[cq * 16 + j * 4 + 3][r] = f2bf(v.w);
    }
    __syncthreads();
    int cl = tid >> 2, kq = tid & 3;
    unsigned short tmp[16];
#pragma unroll
    for (int j = 0; j < 16; ++j) tmp[j] = tile[cl][kq * 16 + j];
    unsigned short* dst = XT + (size_t)(cb + cl) * 2048 + kb + kq * 16;
    *(uint4*)dst = *(uint4*)tmp;
    *(uint4*)(dst + 8) = *(uint4*)(tmp + 8);
}

// ---------------- bf16 MFMA GEMM: C(bf16)[2000,4096] = WCh @ X (via XAh_t) — R22 proven ----------------
__global__ __launch_bounds__(256, 1) void k_gemm_bf(const unsigned short* __restrict__ A,
                                                    const unsigned short* __restrict__ B,
                                                    unsigned short* __restrict__ CH) {
    __shared__ unsigned short As[128][64];   // 16 KB, linear
    __shared__ unsigned short Bs[128][64];
    int tid = threadIdx.x;
    int mb = blockIdx.y * 128, nb = blockIdx.x * 128;
    int w = tid >> 6, lane = tid & 63;
    int wr = w >> 1, wc = w & 1;
    int l15 = lane & 15, l4 = lane >> 4;
    f32x4 acc[4][4] = {};
    int r_base = w * 8 + (lane >> 3);
    int colu = (lane & 7) * 8;
    for (int kt = 0; kt < 32; ++kt) {
        __syncthreads();
#pragma unroll
        for (int c = 0; c < 4; ++c) {
            int row = c * 32 + r_base;
            gload_lds16(A + (size_t)(mb + row) * 2048 + kt * 64 + colu, &As[c * 32 + w * 8][0]);
            gload_lds16(B + (size_t)(nb + row) * 2048 + kt * 64 + colu, &Bs[c * 32 + w * 8][0]);
        }
        __syncthreads();
#pragma unroll
        for (int kk = 0; kk < 2; ++kk) {
            short8v af[4], bfr[4];
#pragma unroll
            for (int f = 0; f < 4; ++f) {
                af[f]  = *(const short8v*)&As[wr * 64 + f * 16 + l15][kk * 32 + l4 * 8];
                bfr[f] = *(const short8v*)&Bs[wc * 64 + f * 16 + l15][kk * 32 + l4 * 8];
            }
#pragma unroll
            for (int fm = 0; fm < 4; ++fm)
#pragma unroll
                for (int fn = 0; fn < 4; ++fn)
                    acc[fm][fn] = __builtin_amdgcn_mfma_f32_16x16x32_bf16(af[fm], bfr[fn], acc[fm][fn], 0, 0, 0);
        }
    }
    unsigned short* epi = (unsigned short*)(&As[0][0]) + (size_t)w * (16 * 72);
    int erow8 = lane >> 3;
    int ecol8 = lane & 7;
#pragma unroll
    for (int fm = 0; fm < 4; ++fm) {
        __syncthreads();
#pragma unroll
        for (int fn = 0; fn < 4; ++fn)
#pragma unroll
            for (int rr = 0; rr < 4; ++rr)
                epi[(l4 * 4 + rr) * 72 + fn * 16 + l15] = f2bf(acc[fm][fn][rr]);
        __syncthreads();
#pragma unroll
        for (int rh = 0; rh < 2; ++rh) {
            int lrow = rh * 8 + erow8;
            int grow = mb + wr * 64 + fm * 16 + lrow;
            if (grow < NN) {
                *(uint4*)(CH + (size_t)grow * THL + nb + wc * 64 + ecol8 * 8)
                    = *(const uint4*)&epi[lrow * 72 + ecol8 * 8];
            }
        }
    }
}

// ---------------- FUSED: fusion (K=128) + relu + xw0 GEMM (K=64) -> xw0 bf16 ----------------
// XC is consumed only by xw0 -> never written to global. xw0 output overwrites the
// x_agg buffer in place (block reads exactly the rows it later writes; row-local).
__global__ __launch_bounds__(256) void k_fusxw(const float* __restrict__ X,
                                               const unsigned short* __restrict__ XAH,
                                               const float* __restrict__ W,
                                               const float* __restrict__ b,
                                               const float* __restrict__ W0,
                                               unsigned short* __restrict__ OUT) {
    __shared__ float Wt[2 * HH][68];
    __shared__ float As[HH][68];
    int tid = threadIdx.x;
    size_t r0 = (size_t)blockIdx.x * 64;
    for (int i = tid; i < HH * 2 * HH; i += 256) { int o = i >> 7, k = i & 127; Wt[k][o] = W[i]; }
    int row = tid >> 2, kq = tid & 3;
    int tx = tid & 15, ty = tid >> 4;
    float acc[4][4] = {};
    __syncthreads();
    {
        const float4* src = (const float4*)(X + (r0 + row) * HH + kq * 16);
#pragma unroll
        for (int j = 0; j < 4; ++j) {
            float4 v = src[j];
            As[kq * 16 + j * 4 + 0][row] = v.x;
            As[kq * 16 + j * 4 + 1][row] = v.y;
            As[kq * 16 + j * 4 + 2][row] = v.z;
            As[kq * 16 + j * 4 + 3][row] = v.w;
        }
    }
    __syncthreads();
#pragma unroll
    for (int k = 0; k < HH; ++k) {
        float4 av = *(const float4*)&As[k][ty * 4];
        float4 wv = *(const float4*)&Wt[k][tx * 4];
        acc[0][0] += av.x * wv.x; acc[0][1] += av.x * wv.y; acc[0][2] += av.x * wv.z; acc[0][3] += av.x * wv.w;
        acc[1][0] += av.y * wv.x; acc[1][1] += av.y * wv.y; acc[1][2] += av.y * wv.z; acc[1][3] += av.y * wv.w;
        acc[2][0] += av.z * wv.x; acc[2][1] += av.z * wv.y; acc[2][2] += av.z * wv.z; acc[2][3] += av.z * wv.w;
        acc[3][0] += av.w * wv.x; acc[3][1] += av.w * wv.y; acc[3][2] += av.w * wv.z; acc[3][3] += av.w * wv.w;
    }
    __syncthreads();
    {
        const uint4* s = (const uint4*)(XAH + (r0 + row) * HH + kq * 16);
        uint4 u0 = s[0], u1 = s[1];
        unsigned short us[16];
        *(uint4*)us = u0; *(uint4*)(us + 8) = u1;
#pragma unroll
        for (int j = 0; j < 16; ++j)
            As[kq * 16 + j][row] = bf2f(us[j]);
    }
    __syncthreads();
#pragma unroll
    for (int k = 0; k < HH; ++k) {
        float4 av = *(const float4*)&As[k][ty * 4];
        float4 wv = *(const float4*)&Wt[HH + k][tx * 4];
        acc[0][0] += av.x * wv.x; acc[0][1] += av.x * wv.y; acc[0][2] += av.x * wv.z; acc[0][3] += av.x * wv.w;
        acc[1][0] += av.y * wv.x; acc[1][1] += av.y * wv.y; acc[1][2] += av.y * wv.z; acc[1][3] += av.y * wv.w;
        acc[2][0] += av.z * wv.x; acc[2][1] += av.z * wv.y; acc[2][2] += av.z * wv.z; acc[2][3] += av.z * wv.w;
        acc[3][0] += av.w * wv.x; acc[3][1] += av.w * wv.y; acc[3][2] += av.w * wv.z; acc[3][3] += av.w * wv.w;
    }
    float4 bv = *(const float4*)(b + tx * 4);
    __syncthreads();   // all reads of As (phase-1 input) done before overwrite
    // stage relu(XC) into As as [k][row]; load W0 (transposed) into Wt[0..63]
#pragma unroll
    for (int ii = 0; ii < 4; ++ii) {
        As[tx * 4 + 0][ty * 4 + ii] = fmaxf(acc[ii][0] + bv.x, 0.f);
        As[tx * 4 + 1][ty * 4 + ii] = fmaxf(acc[ii][1] + bv.y, 0.f);
        As[tx * 4 + 2][ty * 4 + ii] = fmaxf(acc[ii][2] + bv.z, 0.f);
        As[tx * 4 + 3][ty * 4 + ii] = fmaxf(acc[ii][3] + bv.w, 0.f);
    }
    for (int i = tid; i < HH * HH; i += 256) { int o = i >> 6, k = i & 63; Wt[k][o] = W0[i]; }
    __syncthreads();
    // xw0 GEMM: K=64
    float a2[4][4] = {};
#pragma unroll
    for (int k = 0; k < HH; ++k) {
        float4 av = *(const float4*)&As[k][ty * 4];
        float4 wv = *(const float4*)&Wt[k][tx * 4];
        a2[0][0] += av.x * wv.x; a2[0][1] += av.x * wv.y; a2[0][2] += av.x * wv.z; a2[0][3] += av.x * wv.w;
        a2[1][0] += av.y * wv.x; a2[1][1] += av.y * wv.y; a2[1][2] += av.y * wv.z; a2[1][3] += av.y * wv.w;
        a2[2][0] += av.z * wv.x; a2[2][1] += av.z * wv.y; a2[2][2] += av.z * wv.z; a2[2][3] += av.z * wv.w;
        a2[3][0] += av.w * wv.x; a2[3][1] += av.w * wv.y; a2[3][2] += av.w * wv.z; a2[3][3] += av.w * wv.w;
    }
#pragma unroll
    for (int ii = 0; ii < 4; ++ii) {
        unsigned int p0 = (unsigned int)f2bf(a2[ii][0]) | ((unsigned int)f2bf(a2[ii][1]) << 16);
        unsigned int p1 = (unsigned int)f2bf(a2[ii][2]) | ((unsigned int)f2bf(a2[ii][3]) << 16);
        uint2 pk; pk.x = p0; pk.y = p1;
        *(uint2*)(OUT + (r0 + ty * 4 + ii) * HH + tx * 4) = pk;
    }
}

// ---------------- FUSED: agg (CSR, bf16) + bias + BN + relu + xw1 GEMM -> xw1 bf16 ----------------
// Each (dst, ch) block covers 16 complete H-rows of [N*T][H] -> xw is row-local.
__global__ __launch_bounds__(256) void k_aggxw(const unsigned short* __restrict__ XW,
                                               const int* __restrict__ off,
                                               const int* __restrict__ csr_src,
                                               const float* __restrict__ csr_nrm,
                                               const float* __restrict__ bias,
                                               const float* __restrict__ g,
                                               const float* __restrict__ bb,
                                               const float* __restrict__ m,
                                               const float* __restrict__ v,
                                               const float* __restrict__ W1,
                                               unsigned short* __restrict__ OUT) {
    __shared__ float Rs[HH][18];    // [k=h][row 0..15]
    __shared__ float Wt[HH][68];    // [k][o]
    int dst = blockIdx.x, ch = blockIdx.y, tid = threadIdx.x;
    int base = ch * 1024 + tid * 4;
    for (int i = tid; i < HH * HH; i += 256) { int o = i >> 6, k = i & 63; Wt[k][o] = W1[i]; }
    float4 acc = make_float4(0.f, 0.f, 0.f, 0.f);
    int beg = off[dst], end = off[dst + 1];
    for (int e = beg; e < end; ++e) {
        int src = csr_src[e];
        float w = csr_nrm[e];
        uint2 u = *(const uint2*)(XW + (size_t)src * THL + base);
        acc.x += w * bf2f((unsigned short)(u.x & 0xffff));
        acc.y += w * bf2f((unsigned short)(u.x >> 16));
        acc.z += w * bf2f((unsigned short)(u.y & 0xffff));
        acc.w += w * bf2f((unsigned short)(u.y >> 16));
    }
    int h0 = base & 63;             // = (tid&15)*4
    int rloc = tid >> 4;            // local row 0..15
    float4 bs = *(const float4*)(bias + h0);
    float4 gv = *(const float4*)(g + h0);
    float4 vv = *(const float4*)(v + h0);
    float4 mv = *(const float4*)(m + h0);
    float4 bv = *(const float4*)(bb + h0);
    Rs[h0 + 0][rloc] = fmaxf((acc.x + bs.x - mv.x) * rsqrtf(vv.x + EPSBN) * gv.x + bv.x, 0.f);
    Rs[h0 + 1][rloc] = fmaxf((acc.y + bs.y - mv.y) * rsqrtf(vv.y + EPSBN) * gv.y + bv.y, 0.f);
    Rs[h0 + 2][rloc] = fmaxf((acc.z + bs.z - mv.z) * rsqrtf(vv.z + EPSBN) * gv.z + bv.z, 0.f);
    Rs[h0 + 3][rloc] = fmaxf((acc.w + bs.w - mv.w) * rsqrtf(vv.w + EPSBN) * gv.w + bv.w, 0.f);
    __syncthreads();
    // xw1 GEMM: out[rloc][c4*4..] ; thread (r=tid>>4, c4=tid&15)
    int c4 = tid & 15;
    float a2[4] = {0.f, 0.f, 0.f, 0.f};
#pragma unroll
    for (int k = 0; k < HH; ++k) {
        float a = Rs[k][rloc];
        float4 wv = *(const float4*)&Wt[k][c4 * 4];
        a2[0] += a * wv.x; a2[1] += a * wv.y; a2[2] += a * wv.z; a2[3] += a * wv.w;
    }
    size_t grow = (size_t)dst * TT + ch * 16 + rloc;
    unsigned int p0 = (unsigned int)f2bf(a2[0]) | ((unsigned int)f2bf(a2[1]) << 16);
    unsigned int p1 = (unsigned int)f2bf(a2[2]) | ((unsigned int)f2bf(a2[3]) << 16);
    uint2 pk; pk.x = p0; pk.y = p1;
    *(uint2*)(OUT + grow * HH + c4 * 4) = pk;
}

// ---------------- GCN aggregate (CSR, bf16 in) + bias + BN + relu (fp32 out) ----------------
__global__ __launch_bounds__(256) void k_agg(const unsigned short* __restrict__ XW,
                                             const int* __restrict__ off,
                                             const int* __restrict__ csr_src,
                                             const float* __restrict__ csr_nrm,
                                             const float* __restrict__ bias,
                                             const float* __restrict__ g,
                                             const float* __restrict__ bb,
                                             const float* __restrict__ m,
                                             const float* __restrict__ v,
                                             float* __restrict__ OUT) {
    int dst = blockIdx.x, ch = blockIdx.y, tid = threadIdx.x;
    int base = ch * 1024 + tid * 4;
    float4 acc = make_float4(0.f, 0.f, 0.f, 0.f);
    int beg = off[dst], end = off[dst + 1];
    for (int e = beg; e < end; ++e) {
        int src = csr_src[e];
        float w = csr_nrm[e];
        uint2 u = *(const uint2*)(XW + (size_t)src * THL + base);
        acc.x += w * bf2f((unsigned short)(u.x & 0xffff));
        acc.y += w * bf2f((unsigned short)(u.x >> 16));
        acc.z += w * bf2f((unsigned short)(u.y & 0xffff));
        acc.w += w * bf2f((unsigned short)(u.y >> 16));
    }
    int h0 = base & 63;
    float4 bs = *(const float4*)(bias + h0);
    float4 gv = *(const float4*)(g + h0);
    float4 vv = *(const float4*)(v + h0);
    float4 mv = *(const float4*)(m + h0);
    float4 bv = *(const float4*)(bb + h0);
    float4 o;
    o.x = fmaxf((acc.x + bs.x - mv.x) * rsqrtf(vv.x + EPSBN) * gv.x + bv.x, 0.f);
    o.y = fmaxf((acc.y + bs.y - mv.y) * rsqrtf(vv.y + EPSBN) * gv.y + bv.y, 0.f);
    o.z = fmaxf((acc.z + bs.z - mv.z) * rsqrtf(vv.z + EPSBN) * gv.z + bv.z, 0.f);
    o.w = fmaxf((acc.w + bs.w - mv.w) * rsqrtf(vv.w + EPSBN) * gv.w + bv.w, 0.f);
    *(float4*)(OUT + (size_t)dst * THL + base) = o;
}

// ---------------- MFMA 2-layer GRU (R22 best-known): skew + LDS fp32 h + x-prefetch ----------------
__global__ __launch_bounds__(256, 1) void k_gruM(const float* __restrict__ IN,
                                                 const float* __restrict__ wih0, const float* __restrict__ whh0,
                                                 const float* __restrict__ bih0, const float* __restrict__ bhh0,
                                                 const float* __restrict__ wih1, const float* __restrict__ whh1,
                                                 const float* __restrict__ bih1, const float* __restrict__ bhh1,
                                                 float* __restrict__ hout) {
    __shared__ float hf0[NB][68];
    __shared__ float hf1[NB][68];
    __shared__ unsigned short hb0[NB][72];
    __shared__ unsigned short hb1[NB][72];
    int tid = threadIdx.x;
    int w = tid >> 6, lane = tid & 63;
    int l15 = lane & 15, l4 = lane >> 4;
    int nb0 = blockIdx.x * NB;
    short8v bw[4][3][2];
    const float* Wm[4] = { wih0, whh0, wih1, whh1 };
#pragma unroll
    for (int m = 0; m < 4; ++m)
#pragma unroll
        for (int g = 0; g < 3; ++g)
#pragma unroll
            for (int kk = 0; kk < 2; ++kk) {
                const float* src = Wm[m] + (size_t)(64 * g + 16 * w + l15) * HH + kk * 32 + l4 * 8;
                float4 v0 = *(const float4*)src;
                float4 v1 = *(const float4*)(src + 4);
                short8v f;
                f[0] = (short)f2bf(v0.x); f[1] = (short)f2bf(v0.y);
                f[2] = (short)f2bf(v0.z); f[3] = (short)f2bf(v0.w);
                f[4] = (short)f2bf(v1.x); f[5] = (short)f2bf(v1.y);
                f[6] = (short)f2bf(v1.z); f[7] = (short)f2bf(v1.w);
                bw[m][g][kk] = f;
            }
    int jr = 16 * w + l15;
    float b0r = bih0[jr] + bhh0[jr];
    float b0z = bih0[64 + jr] + bhh0[64 + jr];
    float b0n = bih0[128 + jr];
    float h0n = bhh0[128 + jr];
    float b1r = bih1[jr] + bhh1[jr];
    float b1z = bih1[64 + jr] + bhh1[64 + jr];
    float b1n = bih1[128 + jr];
    float h1n = bhh1[128 + jr];
    for (int i = tid; i < NB * 68; i += 256) { ((float*)hf0)[i] = 0.f; ((float*)hf1)[i] = 0.f; }
    for (int i = tid; i < NB * 72; i += 256) { ((unsigned short*)hb0)[i] = 0; ((unsigned short*)hb1)[i] = 0; }
    __syncthreads();
    const float* xb = IN + (size_t)(nb0 + l15) * (TT * HH);
    float4 xv[4];
    {
        const float* xs = xb + 0 * HH + l4 * 8;
        xv[0] = *(const float4*)xs; xv[1] = *(const float4*)(xs + 4);
        const float* xs2 = xb + 0 * HH + 32 + l4 * 8;
        xv[2] = *(const float4*)xs2; xv[3] = *(const float4*)(xs2 + 4);
    }
#pragma unroll 1
    for (int t = 0; t <= TT; ++t) {
        bool act0 = (t < TT);
        bool act1 = (t >= 1);
        short8v ax[2], ah0[2], ah1[2];
#pragma unroll
        for (int kk = 0; kk < 2; ++kk) {
            float4 v0 = xv[kk * 2], v1 = xv[kk * 2 + 1];
            short8v f;
            f[0] = (short)f2bf(v0.x); f[1] = (short)f2bf(v0.y);
            f[2] = (short)f2bf(v0.z); f[3] = (short)f2bf(v0.w);
            f[4] = (short)f2bf(v1.x); f[5] = (short)f2bf(v1.y);
            f[6] = (short)f2bf(v1.z); f[7] = (short)f2bf(v1.w);
            ax[kk] = f;
            ah0[kk] = *(const short8v*)&hb0[l15][kk * 32 + l4 * 8];
            ah1[kk] = *(const short8v*)&hb1[l15][kk * 32 + l4 * 8];
        }
        __syncthreads();
        if (t + 1 < TT) {
            const float* xs = xb + (size_t)(t + 1) * HH + l4 * 8;
            xv[0] = *(const float4*)xs; xv[1] = *(const float4*)(xs + 4);
            const float* xs2 = xb + (size_t)(t + 1) * HH + 32 + l4 * 8;
            xv[2] = *(const float4*)xs2; xv[3] = *(const float4*)(xs2 + 4);
        }
        if (act0) {
            f32x4 gr = { b0r, b0r, b0r, b0r };
            f32x4 gz = { b0z, b0z, b0z, b0z };
            f32x4 gn = { b0n, b0n, b0n, b0n };
            f32x4 hr = { 0.f, 0.f, 0.f, 0.f };
            f32x4 hz = { 0.f, 0.f, 0.f, 0.f };
            f32x4 hn = { h0n, h0n, h0n, h0n };
#pragma unroll
            for (int kk = 0; kk < 2; ++kk) {
                gr = __builtin_amdgcn_mfma_f32_16x16x32_bf16(ax[kk], bw[0][0][kk], gr, 0, 0, 0);
                gz = __builtin_amdgcn_mfma_f32_16x16x32_bf16(ax[kk], bw[0][1][kk], gz, 0, 0, 0);
                gn = __builtin_amdgcn_mfma_f32_16x16x32_bf16(ax[kk], bw[0][2][kk], gn, 0, 0, 0);
                hr = __builtin_amdgcn_mfma_f32_16x16x32_bf16(ah0[kk], bw[1][0][kk], hr, 0, 0, 0);
                hz = __builtin_amdgcn_mfma_f32_16x16x32_bf16(ah0[kk], bw[1][1][kk], hz, 0, 0, 0);
                hn = __builtin_amdgcn_mfma_f32_16x16x32_bf16(ah0[kk], bw[1][2][kk], hn, 0, 0, 0);
            }
#pragma unroll
            for (int i = 0; i < 4; ++i) {
                int node = l4 * 4 + i;
                float r = fsigmoid(gr[i] + hr[i]);
                float z = fsigmoid(gz[i] + hz[i]);
                float nn2 = ftanh(gn[i] + r * hn[i]);
                float ho = hf0[node][jr];
                float hv = (1.f - z) * nn2 + z * ho;
                hf0[node][jr] = hv;
                hb0[node][jr] = f2bf(hv);
            }
        }
        if (act1) {
            f32x4 gr = { b1r, b1r, b1r, b1r };
            f32x4 gz = { b1z, b1z, b1z, b1z };
            f32x4 gn = { b1n, b1n, b1n, b1n };
            f32x4 hr = { 0.f, 0.f, 0.f, 0.f };
            f32x4 hz = { 0.f, 0.f, 0.f, 0.f };
            f32x4 hn = { h1n, h1n, h1n, h1n };
#pragma unroll
            for (int kk = 0; kk < 2; ++kk) {
                gr = __builtin_amdgcn_mfma_f32_16x16x32_bf16(ah0[kk], bw[2][0][kk], gr, 0, 0, 0);
                gz = __builtin_amdgcn_mfma_f32_16x16x32_bf16(ah0[kk], bw[2][1][kk], gz, 0, 0, 0);
                gn = __builtin_amdgcn_mfma_f32_16x16x32_bf16(ah0[kk], bw[2][2][kk], gn, 0, 0, 0);
                hr = __builtin_amdgcn_mfma_f32_16x16x32_bf16(ah1[kk], bw[3][0][kk], hr, 0, 0, 0);
                hz = __builtin_amdgcn_mfma_f32_16x16x32_bf16(ah1[kk], bw[3][1][kk], hz, 0, 0, 0);
                hn = __builtin_amdgcn_mfma_f32_16x16x32_bf16(ah1[kk], bw[3][2][kk], hn, 0, 0, 0);
            }
#pragma unroll
            for (int i = 0; i < 4; ++i) {
                int node = l4 * 4 + i;
                float r = fsigmoid(gr[i] + hr[i]);
                float z = fsigmoid(gz[i] + hz[i]);
                float nn2 = ftanh(gn[i] + r * hn[i]);
                float ho = hf1[node][jr];
                float hv = (1.f - z) * nn2 + z * ho;
                hf1[node][jr] = hv;
                hb1[node][jr] = f2bf(hv);
            }
        }
        __syncthreads();
    }
    for (int i = tid; i < NB * HH; i += 256) {
        int node = i >> 6, j = i & 63;
        hout[(size_t)(nb0 + node) * HH + j] = hf1[node][j];
    }
}

// ---------------- head: BN + relu + linear + log_softmax ----------------
__global__ __launch_bounds__(256) void k_head(const float* __restrict__ Hf,
                                              const float* __restrict__ g, const float* __restrict__ b,
                                              const float* __restrict__ m, const float* __restrict__ v,
                                              const float* __restrict__ W, const float* __restrict__ wb,
                                              float* __restrict__ out) {
    __shared__ float hb[4][HH];
    __shared__ float lg[4][CC];
    int tid = threadIdx.x;
    int n0 = blockIdx.x * 4;
    int wv = tid >> 6, lane = tid & 63;
    int n = n0 + wv;
    float x = Hf[(size_t)n * HH + lane];
    x = (x - m[lane]) * rsqrtf(v[lane] + EPSBN) * g[lane] + b[lane];
    hb[wv][lane] = fmaxf(x, 0.f);
    __syncthreads();
    if (tid < 4 * CC) {
        int nn = tid / CC, c = tid % CC;
        float acc = wb[c];
        for (int f = 0; f < HH; ++f) acc += hb[nn][f] * W[c * HH + f];
        lg[nn][c] = acc;
    }
    __syncthreads();
    if (tid < 4 * CC) {
        int nn = tid / CC, c = tid % CC;
        float mx = -1e30f;
#pragma unroll
        for (int i = 0; i < CC; ++i) mx = fmaxf(mx, lg[nn][i]);
        float s = 0.f;
#pragma unroll
        for (int i = 0; i < CC; ++i) s += __expf(lg[nn][i] - mx);
        out[(size_t)(n0 + nn) * CC + c] = lg[nn][c] - mx - __logf(s);
    }
}

// ---------------- launch ----------------
extern "C" void kernel_launch(void* const* d_in, const int* in_sizes, int n_in,
                              void* d_out, int out_size, void* d_ws, size_t ws_size,
                              hipStream_t stream) {
    const float* x_seq     = (const float*)d_in[0];
    const int*   edge_idx  = (const int*)d_in[1];
    const float* edge_w    = (const float*)d_in[2];
    const float* causal_w  = (const float*)d_in[3];
    const float* lin_in_w  = (const float*)d_in[4];
    const float* lin_in_b  = (const float*)d_in[5];
    const float* fusion_w  = (const float*)d_in[6];
    const float* fusion_b  = (const float*)d_in[7];
    const float* gcn_w0    = (const float*)d_in[8];
    const float* gcn_b0    = (const float*)d_in[9];
    const float* gcn_w1    = (const float*)d_in[10];
    const float* gcn_b1    = (const float*)d_in[11];
    const float* bn0_g = (const float*)d_in[12], *bn0_b = (const float*)d_in[13];
    const float* bn0_m = (const float*)d_in[14], *bn0_v = (const float*)d_in[15];
    const float* bn1_g = (const float*)d_in[16], *bn1_b = (const float*)d_in[17];
    const float* bn1_m = (const float*)d_in[18], *bn1_v = (const float*)d_in[19];
    const float* wih0 = (const float*)d_in[20], *whh0 = (const float*)d_in[21];
    const float* bih0 = (const float*)d_in[22], *bhh0 = (const float*)d_in[23];
    const float* wih1 = (const float*)d_in[24], *whh1 = (const float*)d_in[25];
    const float* bih1 = (const float*)d_in[26], *bhh1 = (const float*)d_in[27];
    const float* bno_g = (const float*)d_in[28], *bno_b = (const float*)d_in[29];
    const float* bno_m = (const float*)d_in[30], *bno_v = (const float*)d_in[31];
    const float* lout_w = (const float*)d_in[32], *lout_b = (const float*)d_in[33];
    float* out = (float*)d_out;

    float* wsf = (float*)d_ws;
    unsigned short* WCH = (unsigned short*)(wsf + OFF_WC);
    float* XA  = wsf + OFF_XA;
    float* XC  = wsf + OFF_XC;
    unsigned short* XAT = (unsigned short*)(wsf + OFF_XC);   // bf16 XAh_t (pre-agg1)
    unsigned short* XBH = (unsigned short*)(wsf + OFF_XB);   // bf16: x_agg, then xw0 (in place)
    unsigned short* XW1 = (unsigned short*)(wsf + OFF_XA);   // bf16 xw1 (XA region, post-fusxw)
    float* DEG = wsf + OFF_DEG;
    int* CNT   = (int*)(wsf + OFF_CNT);
    int* CUR   = (int*)(wsf + OFF_CUR);
    int* OFFP  = (int*)(wsf + OFF_OFF);
    int* CSRS  = (int*)(wsf + OFF_CSRS);
    float* CSRN = wsf + OFF_CSRN;
    float* HST  = wsf + OFF_HST;

    // CSR + degree build
    k_zero<<<8, 256, 0, stream>>>(CNT, CUR, DEG);
    k_count<<<(ETOT + 255) / 256, 256, 0, stream>>>(edge_idx, edge_w, CNT, DEG);
    k_scan<<<1, 1024, 0, stream>>>(CNT, OFFP);
    k_fill<<<(ETOT + 255) / 256, 256, 0, stream>>>(edge_idx, edge_w, DEG, OFFP, CUR, CSRS, CSRN);

    hipMemsetAsync(WCH, 0, (size_t)2048 * 2048 * 2, stream);
    k_softmax<<<NN, 256, 0, stream>>>(causal_w, WCH);
    // lin_in -> XA [N,T,H] fp32
    k_lin2<<<NN, 256, 0, stream>>>(x_seq, lin_in_w, lin_in_b, XA);
    // transpose+cast: XA -> XAh_t bf16 [4096][2048]
    dim3 tg(THL / 64, 2048 / 64);
    k_tr<<<tg, 256, 0, stream>>>(XA, XAT);
    // x_agg = WCh @ X (MFMA bf16) -> XBH (bf16)
    dim3 gg(THL / 128, 2048 / 128);
    k_gemm_bf<<<gg, 256, 0, stream>>>(WCH, XAT, XBH);
    // fusion + relu + xw0 -> XBH (bf16, in place; XC never materialized)
    k_fusxw<<<NN, 256, 0, stream>>>(XA, XBH, fusion_w, fusion_b, gcn_w0, XBH);
    // agg0 + BN0 + relu + xw1 -> XW1 (bf16, XA region)
    dim3 ag(NN, 4);
    k_aggxw<<<ag, 256, 0, stream>>>(XBH, OFFP, CSRS, CSRN, gcn_b0, bn0_g, bn0_b, bn0_m, bn0_v,
                                    gcn_w1, XW1);
    // agg1 + BN1 + relu -> XC (fp32, GRU input)
    k_agg<<<ag, 256, 0, stream>>>(XW1, OFFP, CSRS, CSRN, gcn_b1, bn1_g, bn1_b, bn1_m, bn1_v, XC);

    // MFMA 2-layer GRU (R22 best-known): XC -> final h in HST (125 blocks)
    k_gruM<<<NN / NB, 256, 0, stream>>>(XC, wih0, whh0, bih0, bhh0,
                                        wih1, whh1, bih1, bhh1, HST);

    // head
    k_head<<<NN / 4, 256, 0, stream>>>(HST, bno_g, bno_b, bno_m, bno_v, lout_w, lout_b, out);
}

// Round 26
// 350.598 us; speedup vs baseline: 1.1131x; 1.0247x over previous
//
#include <hip/hip_runtime.h>
#include <hip/hip_bf16.h>
#include <math.h>

#define TT 64
#define NN 2000
#define FIN 32
#define HH 64
#define CC 10
#define EE 32000
#define ETOT 34000   // E + N self loops
#define THL 4096     // T*H
#define EPSBN 1e-5f
#define NB 16        // nodes per GRU block

// ---------------- workspace layout (float offsets) ----------------
#define OFF_WC   0u          // WCh bf16 [2048][2048]
#define OFF_XA   4000000u    // lin_in bf16 [128000][64]; later xw1 bf16 (same shape)
#define OFF_XB   12192000u   // x_agg bf16 C; then xw0 bf16 (in place)
#define OFF_XC   20384000u   // XAh_t bf16 [4096][2048]; then agg1 bf16 out (GRU input)
#define OFF_DEG  28576000u   // 2048
#define OFF_H1   28578048u   // 128,000 (unused)
#define OFF_CNT  28706048u   // int 2048
#define OFF_CUR  28708096u   // int 2048
#define OFF_OFF  28710144u   // int 2064
#define OFF_CSRS 28712208u   // int 34016
#define OFF_CSRN 28746224u   // float 34016
#define OFF_HST  28780240u   // float 128,000  (GRU h-state)

typedef __attribute__((ext_vector_type(8))) short short8v;
typedef __attribute__((ext_vector_type(4))) float f32x4;

__device__ __forceinline__ float fsigmoid(float x) { return 1.f / (1.f + __expf(-x)); }
__device__ __forceinline__ float ftanh(float x) {
    float e = __expf(2.f * x);
    return (e - 1.f) / (e + 1.f);
}
__device__ __forceinline__ unsigned short f2bf(float f) {
    __hip_bfloat16 h = __float2bfloat16(f);
    return *reinterpret_cast<unsigned short*>(&h);
}
__device__ __forceinline__ float bf2f(unsigned short u) {
    unsigned int x = ((unsigned int)u) << 16;
    return __int_as_float(x);
}
// async global->LDS, 16B per lane; LDS dest = wave-uniform base + lane*16 (linear)
__device__ __forceinline__ void gload_lds16(const unsigned short* g, unsigned short* l) {
    __builtin_amdgcn_global_load_lds(
        (const __attribute__((address_space(1))) unsigned int*)g,
        (__attribute__((address_space(3))) unsigned int*)l,
        16, 0, 0);
}

// ---------------- CSR build ----------------
__global__ void k_zero(int* cnt, int* cur, float* deg) {
    int i = blockIdx.x * 256 + threadIdx.x;
    if (i < 2048) { cnt[i] = 0; cur[i] = 0; deg[i] = 0.f; }
}

__global__ void k_count(const int* __restrict__ ei, const float* __restrict__ ew,
                        int* cnt, float* deg) {
    int e = blockIdx.x * 256 + threadIdx.x;
    if (e < ETOT) {
        int dst; float w;
        if (e < EE) { dst = ei[EE + e]; w = ew[e]; }
        else        { dst = e - EE;     w = 1.f; }
        atomicAdd(&cnt[dst], 1);
        atomicAdd(&deg[dst], w);
    }
}

__global__ __launch_bounds__(1024) void k_scan(const int* __restrict__ cnt, int* off) {
    __shared__ int s[2048];
    int tid = threadIdx.x;
    s[tid]        = (tid        < NN) ? cnt[tid]        : 0;
    s[tid + 1024] = (tid + 1024 < NN) ? cnt[tid + 1024] : 0;
    __syncthreads();
    for (int d = 1; d < 2048; d <<= 1) {
        int idx = (tid + 1) * (d << 1) - 1;
        if (idx < 2048) s[idx] += s[idx - d];
        __syncthreads();
    }
    if (tid == 0) s[2047] = 0;
    __syncthreads();
    for (int d = 1024; d >= 1; d >>= 1) {
        int idx = (tid + 1) * (d << 1) - 1;
        if (idx < 2048) { int t = s[idx - d]; s[idx - d] = s[idx]; s[idx] += t; }
        __syncthreads();
    }
    off[tid] = s[tid];
    off[tid + 1024] = s[tid + 1024];
}

__global__ void k_fill(const int* __restrict__ ei, const float* __restrict__ ew,
                       const float* __restrict__ deg, const int* __restrict__ off,
                       int* cur, int* csr_src, float* csr_nrm) {
    int e = blockIdx.x * 256 + threadIdx.x;
    if (e < ETOT) {
        int src, dst; float w;
        if (e < EE) { src = ei[e]; dst = ei[EE + e]; w = ew[e]; }
        else        { src = dst = e - EE;            w = 1.f; }
        float ds = rsqrtf(fmaxf(deg[src], 1e-12f));
        float dd = rsqrtf(fmaxf(deg[dst], 1e-12f));
        int pos = off[dst] + atomicAdd(&cur[dst], 1);
        csr_src[pos] = src;
        csr_nrm[pos] = ds * w * dd;
    }
}

// ---------------- softmax over causal_weight rows -> bf16 WCh [2048 stride] ----------------
__global__ __launch_bounds__(256) void k_softmax(const float* __restrict__ CW,
                                                 unsigned short* __restrict__ WCH) {
    __shared__ float row[NN];
    __shared__ float red[256];
    int r = blockIdx.x, tid = threadIdx.x;
    const float* in = CW + (size_t)r * NN;
    float mx = -1e30f;
    for (int i = tid; i < NN; i += 256) { float v = in[i]; row[i] = v; mx = fmaxf(mx, v); }
    red[tid] = mx; __syncthreads();
    for (int s = 128; s > 0; s >>= 1) {
        if (tid < s) red[tid] = fmaxf(red[tid], red[tid + s]);
        __syncthreads();
    }
    mx = red[0]; __syncthreads();
    float sm = 0.f;
    for (int i = tid; i < NN; i += 256) { float e = __expf(row[i] - mx); row[i] = e; sm += e; }
    red[tid] = sm; __syncthreads();
    for (int s = 128; s > 0; s >>= 1) {
        if (tid < s) red[tid] += red[tid + s];
        __syncthreads();
    }
    float inv = 1.f / red[0];
    unsigned short* out = WCH + (size_t)r * 2048;
    for (int i = tid; i < 2048; i += 256)
        out[i] = (i < NN) ? f2bf(row[i] * inv) : (unsigned short)0;
}

// ---------------- lin_in as tiled GEMM: rows=(n,t), K=32, 64 cols -> bf16 out ----------------
__global__ __launch_bounds__(256) void k_lin2(const float* __restrict__ XS,
                                              const float* __restrict__ W,
                                              const float* __restrict__ b,
                                              unsigned short* __restrict__ OUT) {
    __shared__ float Wt[FIN][68];   // [k][o]
    __shared__ float As[FIN][68];   // [k][row]
    int tid = threadIdx.x;
    int n = blockIdx.x;
    for (int i = tid; i < HH * FIN; i += 256) { int o = i >> 5, k = i & 31; Wt[k][o] = W[i]; }
    int row = tid >> 2, kq = tid & 3;   // row = t
    {
        const float4* src = (const float4*)(XS + ((size_t)row * NN + n) * FIN + kq * 8);
        float4 v0 = src[0], v1 = src[1];
        As[kq * 8 + 0][row] = v0.x; As[kq * 8 + 1][row] = v0.y;
        As[kq * 8 + 2][row] = v0.z; As[kq * 8 + 3][row] = v0.w;
        As[kq * 8 + 4][row] = v1.x; As[kq * 8 + 5][row] = v1.y;
        As[kq * 8 + 6][row] = v1.z; As[kq * 8 + 7][row] = v1.w;
    }
    __syncthreads();
    int tx = tid & 15, ty = tid >> 4;
    float acc[4][4] = {};
#pragma unroll
    for (int k = 0; k < FIN; ++k) {
        float4 av = *(const float4*)&As[k][ty * 4];
        float4 wv = *(const float4*)&Wt[k][tx * 4];
        acc[0][0] += av.x * wv.x; acc[0][1] += av.x * wv.y; acc[0][2] += av.x * wv.z; acc[0][3] += av.x * wv.w;
        acc[1][0] += av.y * wv.x; acc[1][1] += av.y * wv.y; acc[1][2] += av.y * wv.z; acc[1][3] += av.y * wv.w;
        acc[2][0] += av.z * wv.x; acc[2][1] += av.z * wv.y; acc[2][2] += av.z * wv.z; acc[2][3] += av.z * wv.w;
        acc[3][0] += av.w * wv.x; acc[3][1] += av.w * wv.y; acc[3][2] += av.w * wv.z; acc[3][3] += av.w * wv.w;
    }
    float4 bv = *(const float4*)(b + tx * 4);
#pragma unroll
    for (int ii = 0; ii < 4; ++ii) {
        float o0 = fmaxf(acc[ii][0] + bv.x, 0.f);
        float o1 = fmaxf(acc[ii][1] + bv.y, 0.f);
        float o2 = fmaxf(acc[ii][2] + bv.z, 0.f);
        float o3 = fmaxf(acc[ii][3] + bv.w, 0.f);
        unsigned int p0 = (unsigned int)f2bf(o0) | ((unsigned int)f2bf(o1) << 16);
        unsigned int p1 = (unsigned int)f2bf(o2) | ((unsigned int)f2bf(o3) << 16);
        uint2 pk; pk.x = p0; pk.y = p1;
        *(uint2*)(OUT + ((size_t)n * TT + ty * 4 + ii) * HH + tx * 4) = pk;
    }
}

// ---------------- transpose (bf16 in, bf16 out) ----------------
__global__ __launch_bounds__(256) void k_tr(const unsigned short* __restrict__ X,
                                            unsigned short* __restrict__ XT) {
    __shared__ unsigned short tile[64][65];
    int cb = blockIdx.x * 64;
    int kb = blockIdx.y * 64;
    int tid = threadIdx.x;
    int r = tid >> 2, cq = tid & 3;
    unsigned short vals[16];
    if (kb + r < NN) {
        const uint4* src = (const uint4*)(X + (size_t)(kb + r) * THL + cb + cq * 16);
        uint4 u0 = src[0], u1 = src[1];
        *(uint4*)vals = u0; *(uint4*)(vals + 8) = u1;
    } else {
#pragma unroll
        for (int j = 0; j < 16; ++j) vals[j] = 0;   // zero-fill pad rows (kills garbage->NaN path)
    }
#pragma unroll
    for (int j = 0; j < 16; ++j) tile[cq * 16 + j][r] = vals[j];
    __syncthreads();
    int cl = tid >> 2, kq = tid & 3;
    unsigned short tmp[16];
#pragma unroll
    for (int j = 0; j < 16; ++j) tmp[j] = tile[cl][kq * 16 + j];
    unsigned short* dst = XT + (size_t)(cb + cl) * 2048 + kb + kq * 16;
    *(uint4*)dst = *(uint4*)tmp;
    *(uint4*)(dst + 8) = *(uint4*)(tmp + 8);
}

// ---------------- bf16 MFMA GEMM: C(bf16)[2000,4096] = WCh @ X (via XAh_t) — R22 proven ----------------
__global__ __launch_bounds__(256, 1) void k_gemm_bf(const unsigned short* __restrict__ A,
                                                    const unsigned short* __restrict__ B,
                                                    unsigned short* __restrict__ CH) {
    __shared__ unsigned short As[128][64];   // 16 KB, linear
    __shared__ unsigned short Bs[128][64];
    int tid = threadIdx.x;
    int mb = blockIdx.y * 128, nb = blockIdx.x * 128;
    int w = tid >> 6, lane = tid & 63;
    int wr = w >> 1, wc = w & 1;
    int l15 = lane & 15, l4 = lane >> 4;
    f32x4 acc[4][4] = {};
    int r_base = w * 8 + (lane >> 3);
    int colu = (lane & 7) * 8;
    for (int kt = 0; kt < 32; ++kt) {
        __syncthreads();
#pragma unroll
        for (int c = 0; c < 4; ++c) {
            int row = c * 32 + r_base;
            gload_lds16(A + (size_t)(mb + row) * 2048 + kt * 64 + colu, &As[c * 32 + w * 8][0]);
            gload_lds16(B + (size_t)(nb + row) * 2048 + kt * 64 + colu, &Bs[c * 32 + w * 8][0]);
        }
        __syncthreads();
#pragma unroll
        for (int kk = 0; kk < 2; ++kk) {
            short8v af[4], bfr[4];
#pragma unroll
            for (int f = 0; f < 4; ++f) {
                af[f]  = *(const short8v*)&As[wr * 64 + f * 16 + l15][kk * 32 + l4 * 8];
                bfr[f] = *(const short8v*)&Bs[wc * 64 + f * 16 + l15][kk * 32 + l4 * 8];
            }
#pragma unroll
            for (int fm = 0; fm < 4; ++fm)
#pragma unroll
                for (int fn = 0; fn < 4; ++fn)
                    acc[fm][fn] = __builtin_amdgcn_mfma_f32_16x16x32_bf16(af[fm], bfr[fn], acc[fm][fn], 0, 0, 0);
        }
    }
    unsigned short* epi = (unsigned short*)(&As[0][0]) + (size_t)w * (16 * 72);
    int erow8 = lane >> 3;
    int ecol8 = lane & 7;
#pragma unroll
    for (int fm = 0; fm < 4; ++fm) {
        __syncthreads();
#pragma unroll
        for (int fn = 0; fn < 4; ++fn)
#pragma unroll
            for (int rr = 0; rr < 4; ++rr)
                epi[(l4 * 4 + rr) * 72 + fn * 16 + l15] = f2bf(acc[fm][fn][rr]);
        __syncthreads();
#pragma unroll
        for (int rh = 0; rh < 2; ++rh) {
            int lrow = rh * 8 + erow8;
            int grow = mb + wr * 64 + fm * 16 + lrow;
            if (grow < NN) {
                *(uint4*)(CH + (size_t)grow * THL + nb + wc * 64 + ecol8 * 8)
                    = *(const uint4*)&epi[lrow * 72 + ecol8 * 8];
            }
        }
    }
}

// ---------------- FUSED: fusion (K=128, both inputs bf16) + relu + xw0 GEMM -> xw0 bf16 ----------------
__global__ __launch_bounds__(256) void k_fusxw(const unsigned short* __restrict__ X,
                                               const unsigned short* __restrict__ XAH,
                                               const float* __restrict__ W,
                                               const float* __restrict__ b,
                                               const float* __restrict__ W0,
                                               unsigned short* __restrict__ OUT) {
    __shared__ float Wt[2 * HH][68];
    __shared__ float As[HH][68];
    int tid = threadIdx.x;
    size_t r0 = (size_t)blockIdx.x * 64;
    for (int i = tid; i < HH * 2 * HH; i += 256) { int o = i >> 7, k = i & 127; Wt[k][o] = W[i]; }
    int row = tid >> 2, kq = tid & 3;
    int tx = tid & 15, ty = tid >> 4;
    float acc[4][4] = {};
    __syncthreads();
    {
        const uint4* s = (const uint4*)(X + (r0 + row) * HH + kq * 16);
        uint4 u0 = s[0], u1 = s[1];
        unsigned short us[16];
        *(uint4*)us = u0; *(uint4*)(us + 8) = u1;
#pragma unroll
        for (int j = 0; j < 16; ++j)
            As[kq * 16 + j][row] = bf2f(us[j]);
    }
    __syncthreads();
#pragma unroll
    for (int k = 0; k < HH; ++k) {
        float4 av = *(const float4*)&As[k][ty * 4];
        float4 wv = *(const float4*)&Wt[k][tx * 4];
        acc[0][0] += av.x * wv.x; acc[0][1] += av.x * wv.y; acc[0][2] += av.x * wv.z; acc[0][3] += av.x * wv.w;
        acc[1][0] += av.y * wv.x; acc[1][1] += av.y * wv.y; acc[1][2] += av.y * wv.z; acc[1][3] += av.y * wv.w;
        acc[2][0] += av.z * wv.x; acc[2][1] += av.z * wv.y; acc[2][2] += av.z * wv.z; acc[2][3] += av.z * wv.w;
        acc[3][0] += av.w * wv.x; acc[3][1] += av.w * wv.y; acc[3][2] += av.w * wv.z; acc[3][3] += av.w * wv.w;
    }
    __syncthreads();
    {
        const uint4* s = (const uint4*)(XAH + (r0 + row) * HH + kq * 16);
        uint4 u0 = s[0], u1 = s[1];
        unsigned short us[16];
        *(uint4*)us = u0; *(uint4*)(us + 8) = u1;
#pragma unroll
        for (int j = 0; j < 16; ++j)
            As[kq * 16 + j][row] = bf2f(us[j]);
    }
    __syncthreads();
#pragma unroll
    for (int k = 0; k < HH; ++k) {
        float4 av = *(const float4*)&As[k][ty * 4];
        float4 wv = *(const float4*)&Wt[HH + k][tx * 4];
        acc[0][0] += av.x * wv.x; acc[0][1] += av.x * wv.y; acc[0][2] += av.x * wv.z; acc[0][3] += av.x * wv.w;
        acc[1][0] += av.y * wv.x; acc[1][1] += av.y * wv.y; acc[1][2] += av.y * wv.z; acc[1][3] += av.y * wv.w;
        acc[2][0] += av.z * wv.x; acc[2][1] += av.z * wv.y; acc[2][2] += av.z * wv.z; acc[2][3] += av.z * wv.w;
        acc[3][0] += av.w * wv.x; acc[3][1] += av.w * wv.y; acc[3][2] += av.w * wv.z; acc[3][3] += av.w * wv.w;
    }
    float4 bv = *(const float4*)(b + tx * 4);
    __syncthreads();   // all reads of As (phase-1 input) done before overwrite
    // stage relu(XC) into As as [k][row]; load W0 (transposed) into Wt[0..63]
#pragma unroll
    for (int ii = 0; ii < 4; ++ii) {
        As[tx * 4 + 0][ty * 4 + ii] = fmaxf(acc[ii][0] + bv.x, 0.f);
        As[tx * 4 + 1][ty * 4 + ii] = fmaxf(acc[ii][1] + bv.y, 0.f);
        As[tx * 4 + 2][ty * 4 + ii] = fmaxf(acc[ii][2] + bv.z, 0.f);
        As[tx * 4 + 3][ty * 4 + ii] = fmaxf(acc[ii][3] + bv.w, 0.f);
    }
    for (int i = tid; i < HH * HH; i += 256) { int o = i >> 6, k = i & 63; Wt[k][o] = W0[i]; }
    __syncthreads();
    // xw0 GEMM: K=64
    float a2[4][4] = {};
#pragma unroll
    for (int k = 0; k < HH; ++k) {
        float4 av = *(const float4*)&As[k][ty * 4];
        float4 wv = *(const float4*)&Wt[k][tx * 4];
        a2[0][0] += av.x * wv.x; a2[0][1] += av.x * wv.y; a2[0][2] += av.x * wv.z; a2[0][3] += av.x * wv.w;
        a2[1][0] += av.y * wv.x; a2[1][1] += av.y * wv.y; a2[1][2] += av.y * wv.z; a2[1][3] += av.y * wv.w;
        a2[2][0] += av.z * wv.x; a2[2][1] += av.z * wv.y; a2[2][2] += av.z * wv.z; a2[2][3] += av.z * wv.w;
        a2[3][0] += av.w * wv.x; a2[3][1] += av.w * wv.y; a2[3][2] += av.w * wv.z; a2[3][3] += av.w * wv.w;
    }
#pragma unroll
    for (int ii = 0; ii < 4; ++ii) {
        unsigned int p0 = (unsigned int)f2bf(a2[ii][0]) | ((unsigned int)f2bf(a2[ii][1]) << 16);
        unsigned int p1 = (unsigned int)f2bf(a2[ii][2]) | ((unsigned int)f2bf(a2[ii][3]) << 16);
        uint2 pk; pk.x = p0; pk.y = p1;
        *(uint2*)(OUT + (r0 + ty * 4 + ii) * HH + tx * 4) = pk;
    }
}

// ---------------- FUSED: agg (CSR, bf16) + bias + BN + relu + xw1 GEMM -> xw1 bf16 ----------------
__global__ __launch_bounds__(256) void k_aggxw(const unsigned short* __restrict__ XW,
                                               const int* __restrict__ off,
                                               const int* __restrict__ csr_src,
                                               const float* __restrict__ csr_nrm,
                                               const float* __restrict__ bias,
                                               const float* __restrict__ g,
                                               const float* __restrict__ bb,
                                               const float* __restrict__ m,
                                               const float* __restrict__ v,
                                               const float* __restrict__ W1,
                                               unsigned short* __restrict__ OUT) {
    __shared__ float Rs[HH][18];    // [k=h][row 0..15]
    __shared__ float Wt[HH][68];    // [k][o]
    int dst = blockIdx.x, ch = blockIdx.y, tid = threadIdx.x;
    int base = ch * 1024 + tid * 4;
    for (int i = tid; i < HH * HH; i += 256) { int o = i >> 6, k = i & 63; Wt[k][o] = W1[i]; }
    float4 acc = make_float4(0.f, 0.f, 0.f, 0.f);
    int beg = off[dst], end = off[dst + 1];
    for (int e = beg; e < end; ++e) {
        int src = csr_src[e];
        float w = csr_nrm[e];
        uint2 u = *(const uint2*)(XW + (size_t)src * THL + base);
        acc.x += w * bf2f((unsigned short)(u.x & 0xffff));
        acc.y += w * bf2f((unsigned short)(u.x >> 16));
        acc.z += w * bf2f((unsigned short)(u.y & 0xffff));
        acc.w += w * bf2f((unsigned short)(u.y >> 16));
    }
    int h0 = base & 63;             // = (tid&15)*4
    int rloc = tid >> 4;            // local row 0..15
    float4 bs = *(const float4*)(bias + h0);
    float4 gv = *(const float4*)(g + h0);
    float4 vv = *(const float4*)(v + h0);
    float4 mv = *(const float4*)(m + h0);
    float4 bv = *(const float4*)(bb + h0);
    Rs[h0 + 0][rloc] = fmaxf((acc.x + bs.x - mv.x) * rsqrtf(vv.x + EPSBN) * gv.x + bv.x, 0.f);
    Rs[h0 + 1][rloc] = fmaxf((acc.y + bs.y - mv.y) * rsqrtf(vv.y + EPSBN) * gv.y + bv.y, 0.f);
    Rs[h0 + 2][rloc] = fmaxf((acc.z + bs.z - mv.z) * rsqrtf(vv.z + EPSBN) * gv.z + bv.z, 0.f);
    Rs[h0 + 3][rloc] = fmaxf((acc.w + bs.w - mv.w) * rsqrtf(vv.w + EPSBN) * gv.w + bv.w, 0.f);
    __syncthreads();
    // xw1 GEMM: out[rloc][c4*4..] ; thread (r=tid>>4, c4=tid&15)
    int c4 = tid & 15;
    float a2[4] = {0.f, 0.f, 0.f, 0.f};
#pragma unroll
    for (int k = 0; k < HH; ++k) {
        float a = Rs[k][rloc];
        float4 wv = *(const float4*)&Wt[k][c4 * 4];
        a2[0] += a * wv.x; a2[1] += a * wv.y; a2[2] += a * wv.z; a2[3] += a * wv.w;
    }
    size_t grow = (size_t)dst * TT + ch * 16 + rloc;
    unsigned int p0 = (unsigned int)f2bf(a2[0]) | ((unsigned int)f2bf(a2[1]) << 16);
    unsigned int p1 = (unsigned int)f2bf(a2[2]) | ((unsigned int)f2bf(a2[3]) << 16);
    uint2 pk; pk.x = p0; pk.y = p1;
    *(uint2*)(OUT + grow * HH + c4 * 4) = pk;
}

// ---------------- GCN aggregate (CSR, bf16 in) + bias + BN + relu -> bf16 out (GRU input) ----------------
__global__ __launch_bounds__(256) void k_agg(const unsigned short* __restrict__ XW,
                                             const int* __restrict__ off,
                                             const int* __restrict__ csr_src,
                                             const float* __restrict__ csr_nrm,
                                             const float* __restrict__ bias,
                                             const float* __restrict__ g,
                                             const float* __restrict__ bb,
                                             const float* __restrict__ m,
                                             const float* __restrict__ v,
                                             unsigned short* __restrict__ OUT) {
    int dst = blockIdx.x, ch = blockIdx.y, tid = threadIdx.x;
    int base = ch * 1024 + tid * 4;
    float4 acc = make_float4(0.f, 0.f, 0.f, 0.f);
    int beg = off[dst], end = off[dst + 1];
    for (int e = beg; e < end; ++e) {
        int src = csr_src[e];
        float w = csr_nrm[e];
        uint2 u = *(const uint2*)(XW + (size_t)src * THL + base);
        acc.x += w * bf2f((unsigned short)(u.x & 0xffff));
        acc.y += w * bf2f((unsigned short)(u.x >> 16));
        acc.z += w * bf2f((unsigned short)(u.y & 0xffff));
        acc.w += w * bf2f((unsigned short)(u.y >> 16));
    }
    int h0 = base & 63;
    float4 bs = *(const float4*)(bias + h0);
    float4 gv = *(const float4*)(g + h0);
    float4 vv = *(const float4*)(v + h0);
    float4 mv = *(const float4*)(m + h0);
    float4 bv = *(const float4*)(bb + h0);
    float o0 = fmaxf((acc.x + bs.x - mv.x) * rsqrtf(vv.x + EPSBN) * gv.x + bv.x, 0.f);
    float o1 = fmaxf((acc.y + bs.y - mv.y) * rsqrtf(vv.y + EPSBN) * gv.y + bv.y, 0.f);
    float o2 = fmaxf((acc.z + bs.z - mv.z) * rsqrtf(vv.z + EPSBN) * gv.z + bv.z, 0.f);
    float o3 = fmaxf((acc.w + bs.w - mv.w) * rsqrtf(vv.w + EPSBN) * gv.w + bv.w, 0.f);
    // bf16 here is bit-identical to gruM's former per-step f2bf of the same fp32 values
    unsigned int p0 = (unsigned int)f2bf(o0) | ((unsigned int)f2bf(o1) << 16);
    unsigned int p1 = (unsigned int)f2bf(o2) | ((unsigned int)f2bf(o3) << 16);
    uint2 pk; pk.x = p0; pk.y = p1;
    *(uint2*)(OUT + (size_t)dst * THL + base) = pk;
}

// ---------------- MFMA 2-layer GRU (R22 structure): skew + LDS fp32 h + bf16-x prefetch ----------------
__global__ __launch_bounds__(256, 1) void k_gruM(const unsigned short* __restrict__ IN,
                                                 const float* __restrict__ wih0, const float* __restrict__ whh0,
                                                 const float* __restrict__ bih0, const float* __restrict__ bhh0,
                                                 const float* __restrict__ wih1, const float* __restrict__ whh1,
                                                 const float* __restrict__ bih1, const float* __restrict__ bhh1,
                                                 float* __restrict__ hout) {
    __shared__ float hf0[NB][68];
    __shared__ float hf1[NB][68];
    __shared__ unsigned short hb0[NB][72];
    __shared__ unsigned short hb1[NB][72];
    int tid = threadIdx.x;
    int w = tid >> 6, lane = tid & 63;
    int l15 = lane & 15, l4 = lane >> 4;
    int nb0 = blockIdx.x * NB;
    short8v bw[4][3][2];
    const float* Wm[4] = { wih0, whh0, wih1, whh1 };
#pragma unroll
    for (int m = 0; m < 4; ++m)
#pragma unroll
        for (int g = 0; g < 3; ++g)
#pragma unroll
            for (int kk = 0; kk < 2; ++kk) {
                const float* src = Wm[m] + (size_t)(64 * g + 16 * w + l15) * HH + kk * 32 + l4 * 8;
                float4 v0 = *(const float4*)src;
                float4 v1 = *(const float4*)(src + 4);
                short8v f;
                f[0] = (short)f2bf(v0.x); f[1] = (short)f2bf(v0.y);
                f[2] = (short)f2bf(v0.z); f[3] = (short)f2bf(v0.w);
                f[4] = (short)f2bf(v1.x); f[5] = (short)f2bf(v1.y);
                f[6] = (short)f2bf(v1.z); f[7] = (short)f2bf(v1.w);
                bw[m][g][kk] = f;
            }
    int jr = 16 * w + l15;
    float b0r = bih0[jr] + bhh0[jr];
    float b0z = bih0[64 + jr] + bhh0[64 + jr];
    float b0n = bih0[128 + jr];
    float h0n = bhh0[128 + jr];
    float b1r = bih1[jr] + bhh1[jr];
    float b1z = bih1[64 + jr] + bhh1[64 + jr];
    float b1n = bih1[128 + jr];
    float h1n = bhh1[128 + jr];
    for (int i = tid; i < NB * 68; i += 256) { ((float*)hf0)[i] = 0.f; ((float*)hf1)[i] = 0.f; }
    for (int i = tid; i < NB * 72; i += 256) { ((unsigned short*)hb0)[i] = 0; ((unsigned short*)hb1)[i] = 0; }
    __syncthreads();
    const unsigned short* xb = IN + (size_t)(nb0 + l15) * (TT * HH);
    // prefetch x(0) as bf16 (values identical to former fp32->f2bf path)
    uint4 xu[2];
    xu[0] = *(const uint4*)(xb + l4 * 8);
    xu[1] = *(const uint4*)(xb + 32 + l4 * 8);
#pragma unroll 1
    for (int t = 0; t <= TT; ++t) {
        bool act0 = (t < TT);
        bool act1 = (t >= 1);
        short8v ax[2], ah0[2], ah1[2];
        ax[0] = *(const short8v*)&xu[0];
        ax[1] = *(const short8v*)&xu[1];
#pragma unroll
        for (int kk = 0; kk < 2; ++kk) {
            ah0[kk] = *(const short8v*)&hb0[l15][kk * 32 + l4 * 8];
            ah1[kk] = *(const short8v*)&hb1[l15][kk * 32 + l4 * 8];
        }
        __syncthreads();
        if (t + 1 < TT) {
            const unsigned short* xs = xb + (size_t)(t + 1) * HH;
            xu[0] = *(const uint4*)(xs + l4 * 8);
            xu[1] = *(const uint4*)(xs + 32 + l4 * 8);
        }
        if (act0) {
            f32x4 gr = { b0r, b0r, b0r, b0r };
            f32x4 gz = { b0z, b0z, b0z, b0z };
            f32x4 gn = { b0n, b0n, b0n, b0n };
            f32x4 hr = { 0.f, 0.f, 0.f, 0.f };
            f32x4 hz = { 0.f, 0.f, 0.f, 0.f };
            f32x4 hn = { h0n, h0n, h0n, h0n };
#pragma unroll
            for (int kk = 0; kk < 2; ++kk) {
                gr = __builtin_amdgcn_mfma_f32_16x16x32_bf16(ax[kk], bw[0][0][kk], gr, 0, 0, 0);
                gz = __builtin_amdgcn_mfma_f32_16x16x32_bf16(ax[kk], bw[0][1][kk], gz, 0, 0, 0);
                gn = __builtin_amdgcn_mfma_f32_16x16x32_bf16(ax[kk], bw[0][2][kk], gn, 0, 0, 0);
                hr = __builtin_amdgcn_mfma_f32_16x16x32_bf16(ah0[kk], bw[1][0][kk], hr, 0, 0, 0);
                hz = __builtin_amdgcn_mfma_f32_16x16x32_bf16(ah0[kk], bw[1][1][kk], hz, 0, 0, 0);
                hn = __builtin_amdgcn_mfma_f32_16x16x32_bf16(ah0[kk], bw[1][2][kk], hn, 0, 0, 0);
            }
#pragma unroll
            for (int i = 0; i < 4; ++i) {
                int node = l4 * 4 + i;
                float r = fsigmoid(gr[i] + hr[i]);
                float z = fsigmoid(gz[i] + hz[i]);
                float nn2 = ftanh(gn[i] + r * hn[i]);
                float ho = hf0[node][jr];
                float hv = (1.f - z) * nn2 + z * ho;
                hf0[node][jr] = hv;
                hb0[node][jr] = f2bf(hv);
            }
        }
        if (act1) {
            f32x4 gr = { b1r, b1r, b1r, b1r };
            f32x4 gz = { b1z, b1z, b1z, b1z };
            f32x4 gn = { b1n, b1n, b1n, b1n };
            f32x4 hr = { 0.f, 0.f, 0.f, 0.f };
            f32x4 hz = { 0.f, 0.f, 0.f, 0.f };
            f32x4 hn = { h1n, h1n, h1n, h1n };
#pragma unroll
            for (int kk = 0; kk < 2; ++kk) {
                gr = __builtin_amdgcn_mfma_f32_16x16x32_bf16(ah0[kk], bw[2][0][kk], gr, 0, 0, 0);
                gz = __builtin_amdgcn_mfma_f32_16x16x32_bf16(ah0[kk], bw[2][1][kk], gz, 0, 0, 0);
                gn = __builtin_amdgcn_mfma_f32_16x16x32_bf16(ah0[kk], bw[2][2][kk], gn, 0, 0, 0);
                hr = __builtin_amdgcn_mfma_f32_16x16x32_bf16(ah1[kk], bw[3][0][kk], hr, 0, 0, 0);
                hz = __builtin_amdgcn_mfma_f32_16x16x32_bf16(ah1[kk], bw[3][1][kk], hz, 0, 0, 0);
                hn = __builtin_amdgcn_mfma_f32_16x16x32_bf16(ah1[kk], bw[3][2][kk], hn, 0, 0, 0);
            }
#pragma unroll
            for (int i = 0; i < 4; ++i) {
                int node = l4 * 4 + i;
                float r = fsigmoid(gr[i] + hr[i]);
                float z = fsigmoid(gz[i] + hz[i]);
                float nn2 = ftanh(gn[i] + r * hn[i]);
                float ho = hf1[node][jr];
                float hv = (1.f - z) * nn2 + z * ho;
                hf1[node][jr] = hv;
                hb1[node][jr] = f2bf(hv);
            }
        }
        __syncthreads();
    }
    for (int i = tid; i < NB * HH; i += 256) {
        int node = i >> 6, j = i & 63;
        hout[(size_t)(nb0 + node) * HH + j] = hf1[node][j];
    }
}

// ---------------- head: BN + relu + linear + log_softmax ----------------
__global__ __launch_bounds__(256) void k_head(const float* __restrict__ Hf,
                                              const float* __restrict__ g, const float* __restrict__ b,
                                              const float* __restrict__ m, const float* __restrict__ v,
                                              const float* __restrict__ W, const float* __restrict__ wb,
                                              float* __restrict__ out) {
    __shared__ float hb[4][HH];
    __shared__ float lg[4][CC];
    int tid = threadIdx.x;
    int n0 = blockIdx.x * 4;
    int wv = tid >> 6, lane = tid & 63;
    int n = n0 + wv;
    float x = Hf[(size_t)n * HH + lane];
    x = (x - m[lane]) * rsqrtf(v[lane] + EPSBN) * g[lane] + b[lane];
    hb[wv][lane] = fmaxf(x, 0.f);
    __syncthreads();
    if (tid < 4 * CC) {
        int nn = tid / CC, c = tid % CC;
        float acc = wb[c];
        for (int f = 0; f < HH; ++f) acc += hb[nn][f] * W[c * HH + f];
        lg[nn][c] = acc;
    }
    __syncthreads();
    if (tid < 4 * CC) {
        int nn = tid / CC, c = tid % CC;
        float mx = -1e30f;
#pragma unroll
        for (int i = 0; i < CC; ++i) mx = fmaxf(mx, lg[nn][i]);
        float s = 0.f;
#pragma unroll
        for (int i = 0; i < CC; ++i) s += __expf(lg[nn][i] - mx);
        out[(size_t)(n0 + nn) * CC + c] = lg[nn][c] - mx - __logf(s);
    }
}

// ---------------- launch ----------------
extern "C" void kernel_launch(void* const* d_in, const int* in_sizes, int n_in,
                              void* d_out, int out_size, void* d_ws, size_t ws_size,
                              hipStream_t stream) {
    const float* x_seq     = (const float*)d_in[0];
    const int*   edge_idx  = (const int*)d_in[1];
    const float* edge_w    = (const float*)d_in[2];
    const float* causal_w  = (const float*)d_in[3];
    const float* lin_in_w  = (const float*)d_in[4];
    const float* lin_in_b  = (const float*)d_in[5];
    const float* fusion_w  = (const float*)d_in[6];
    const float* fusion_b  = (const float*)d_in[7];
    const float* gcn_w0    = (const float*)d_in[8];
    const float* gcn_b0    = (const float*)d_in[9];
    const float* gcn_w1    = (const float*)d_in[10];
    const float* gcn_b1    = (const float*)d_in[11];
    const float* bn0_g = (const float*)d_in[12], *bn0_b = (const float*)d_in[13];
    const float* bn0_m = (const float*)d_in[14], *bn0_v = (const float*)d_in[15];
    const float* bn1_g = (const float*)d_in[16], *bn1_b = (const float*)d_in[17];
    const float* bn1_m = (const float*)d_in[18], *bn1_v = (const float*)d_in[19];
    const float* wih0 = (const float*)d_in[20], *whh0 = (const float*)d_in[21];
    const float* bih0 = (const float*)d_in[22], *bhh0 = (const float*)d_in[23];
    const float* wih1 = (const float*)d_in[24], *whh1 = (const float*)d_in[25];
    const float* bih1 = (const float*)d_in[26], *bhh1 = (const float*)d_in[27];
    const float* bno_g = (const float*)d_in[28], *bno_b = (const float*)d_in[29];
    const float* bno_m = (const float*)d_in[30], *bno_v = (const float*)d_in[31];
    const float* lout_w = (const float*)d_in[32], *lout_b = (const float*)d_in[33];
    float* out = (float*)d_out;

    float* wsf = (float*)d_ws;
    unsigned short* WCH = (unsigned short*)(wsf + OFF_WC);
    unsigned short* XLH = (unsigned short*)(wsf + OFF_XA);   // lin_in bf16 [128000][64]
    unsigned short* XAT = (unsigned short*)(wsf + OFF_XC);   // bf16 XAh_t [4096][2048]
    unsigned short* XBH = (unsigned short*)(wsf + OFF_XB);   // bf16: x_agg, then xw0 (in place)
    unsigned short* XW1 = (unsigned short*)(wsf + OFF_XA);   // bf16 xw1 (XA region, post-fusxw)
    unsigned short* XCH = (unsigned short*)(wsf + OFF_XC);   // bf16 agg1 out (GRU input)
    float* DEG = wsf + OFF_DEG;
    int* CNT   = (int*)(wsf + OFF_CNT);
    int* CUR   = (int*)(wsf + OFF_CUR);
    int* OFFP  = (int*)(wsf + OFF_OFF);
    int* CSRS  = (int*)(wsf + OFF_CSRS);
    float* CSRN = wsf + OFF_CSRN;
    float* HST  = wsf + OFF_HST;

    // CSR + degree build
    k_zero<<<8, 256, 0, stream>>>(CNT, CUR, DEG);
    k_count<<<(ETOT + 255) / 256, 256, 0, stream>>>(edge_idx, edge_w, CNT, DEG);
    k_scan<<<1, 1024, 0, stream>>>(CNT, OFFP);
    k_fill<<<(ETOT + 255) / 256, 256, 0, stream>>>(edge_idx, edge_w, DEG, OFFP, CUR, CSRS, CSRN);

    hipMemsetAsync(WCH, 0, (size_t)2048 * 2048 * 2, stream);
    k_softmax<<<NN, 256, 0, stream>>>(causal_w, WCH);
    // lin_in -> XLH bf16 [N*T][H]
    k_lin2<<<NN, 256, 0, stream>>>(x_seq, lin_in_w, lin_in_b, XLH);
    // transpose: XLH -> XAh_t bf16 [4096][2048] (zero-fill pad rows)
    dim3 tg(THL / 64, 2048 / 64);
    k_tr<<<tg, 256, 0, stream>>>(XLH, XAT);
    // x_agg = WCh @ X (MFMA bf16) -> XBH (bf16)
    dim3 gg(THL / 128, 2048 / 128);
    k_gemm_bf<<<gg, 256, 0, stream>>>(WCH, XAT, XBH);
    // fusion + relu + xw0 -> XBH (bf16, in place; fusion intermediate never materialized)
    k_fusxw<<<NN, 256, 0, stream>>>(XLH, XBH, fusion_w, fusion_b, gcn_w0, XBH);
    // agg0 + BN0 + relu + xw1 -> XW1 (bf16, XA region; XLH dead after fusxw)
    dim3 ag(NN, 4);
    k_aggxw<<<ag, 256, 0, stream>>>(XBH, OFFP, CSRS, CSRN, gcn_b0, bn0_g, bn0_b, bn0_m, bn0_v,
                                    gcn_w1, XW1);
    // agg1 + BN1 + relu -> XCH (bf16, GRU input; XAT dead after gemm)
    k_agg<<<ag, 256, 0, stream>>>(XW1, OFFP, CSRS, CSRN, gcn_b1, bn1_g, bn1_b, bn1_m, bn1_v, XCH);

    // MFMA 2-layer GRU (bf16 input): XCH -> final h in HST (125 blocks)
    k_gruM<<<NN / NB, 256, 0, stream>>>(XCH, wih0, whh0, bih0, bhh0,
                                        wih1, whh1, bih1, bhh1, HST);

    // head
    k_head<<<NN / 4, 256, 0, stream>>>(HST, bno_g, bno_b, bno_m, bno_v, lout_w, lout_b, out);
}

// Round 27
// 329.120 us; speedup vs baseline: 1.1857x; 1.0653x over previous
//
#include <hip/hip_runtime.h>
#include <hip/hip_bf16.h>
#include <math.h>

#define TT 64
#define NN 2000
#define FIN 32
#define HH 64
#define CC 10
#define EE 32000
#define ETOT 34000   // E + N self loops
#define THL 4096     // T*H
#define EPSBN 1e-5f
#define NB 16        // nodes per GRU block

// ---------------- workspace layout (float offsets) ----------------
#define OFF_WC   0u          // WCh bf16 [2048][2048]
#define OFF_XA   4000000u    // lin_in bf16 [128000][64]; later xw1 bf16 (same shape)
#define OFF_XB   12192000u   // x_agg bf16 C; then xw0 bf16 (in place)
#define OFF_XC   20384000u   // XAh_t bf16 [4096][2048]; then agg1 bf16 out (GRU input)
#define OFF_DEG  28576000u   // 2048
#define OFF_H1   28578048u   // 128,000 (unused)
#define OFF_CNT  28706048u   // int 2048
#define OFF_CUR  28708096u   // int 2048
#define OFF_OFF  28710144u   // int 2064
#define OFF_CSRS 28712208u   // int 34016
#define OFF_CSRN 28746224u   // float 34016
#define OFF_HST  28780240u   // float 128,000  (GRU h-state)

typedef __attribute__((ext_vector_type(8))) short short8v;
typedef __attribute__((ext_vector_type(4))) float f32x4;

__device__ __forceinline__ float fsigmoid(float x) { return 1.f / (1.f + __expf(-x)); }
__device__ __forceinline__ float ftanh(float x) {
    float e = __expf(2.f * x);
    return (e - 1.f) / (e + 1.f);
}
__device__ __forceinline__ unsigned short f2bf(float f) {
    __hip_bfloat16 h = __float2bfloat16(f);
    return *reinterpret_cast<unsigned short*>(&h);
}
__device__ __forceinline__ float bf2f(unsigned short u) {
    unsigned int x = ((unsigned int)u) << 16;
    return __int_as_float(x);
}
// async global->LDS, 16B per lane; LDS dest = wave-uniform base + lane*16 (linear)
__device__ __forceinline__ void gload_lds16(const unsigned short* g, unsigned short* l) {
    __builtin_amdgcn_global_load_lds(
        (const __attribute__((address_space(1))) unsigned int*)g,
        (__attribute__((address_space(3))) unsigned int*)l,
        16, 0, 0);
}

// ---------------- CSR build ----------------
__global__ void k_zero(int* cnt, int* cur, float* deg) {
    int i = blockIdx.x * 256 + threadIdx.x;
    if (i < 2048) { cnt[i] = 0; cur[i] = 0; deg[i] = 0.f; }
}

__global__ void k_count(const int* __restrict__ ei, const float* __restrict__ ew,
                        int* cnt, float* deg) {
    int e = blockIdx.x * 256 + threadIdx.x;
    if (e < ETOT) {
        int dst; float w;
        if (e < EE) { dst = ei[EE + e]; w = ew[e]; }
        else        { dst = e - EE;     w = 1.f; }
        atomicAdd(&cnt[dst], 1);
        atomicAdd(&deg[dst], w);
    }
}

__global__ __launch_bounds__(1024) void k_scan(const int* __restrict__ cnt, int* off) {
    __shared__ int s[2048];
    int tid = threadIdx.x;
    s[tid]        = (tid        < NN) ? cnt[tid]        : 0;
    s[tid + 1024] = (tid + 1024 < NN) ? cnt[tid + 1024] : 0;
    __syncthreads();
    for (int d = 1; d < 2048; d <<= 1) {
        int idx = (tid + 1) * (d << 1) - 1;
        if (idx < 2048) s[idx] += s[idx - d];
        __syncthreads();
    }
    if (tid == 0) s[2047] = 0;
    __syncthreads();
    for (int d = 1024; d >= 1; d >>= 1) {
        int idx = (tid + 1) * (d << 1) - 1;
        if (idx < 2048) { int t = s[idx - d]; s[idx - d] = s[idx]; s[idx] += t; }
        __syncthreads();
    }
    off[tid] = s[tid];
    off[tid + 1024] = s[tid + 1024];
}

__global__ void k_fill(const int* __restrict__ ei, const float* __restrict__ ew,
                       const float* __restrict__ deg, const int* __restrict__ off,
                       int* cur, int* csr_src, float* csr_nrm) {
    int e = blockIdx.x * 256 + threadIdx.x;
    if (e < ETOT) {
        int src, dst; float w;
        if (e < EE) { src = ei[e]; dst = ei[EE + e]; w = ew[e]; }
        else        { src = dst = e - EE;            w = 1.f; }
        float ds = rsqrtf(fmaxf(deg[src], 1e-12f));
        float dd = rsqrtf(fmaxf(deg[dst], 1e-12f));
        int pos = off[dst] + atomicAdd(&cur[dst], 1);
        csr_src[pos] = src;
        csr_nrm[pos] = ds * w * dd;
    }
}

// ---------------- softmax over causal_weight rows -> bf16 WCh [2048 stride] ----------------
// grid = 2048: rows >= NN write zeros (replaces the 8 MB hipMemsetAsync)
__global__ __launch_bounds__(256) void k_softmax(const float* __restrict__ CW,
                                                 unsigned short* __restrict__ WCH) {
    int r = blockIdx.x, tid = threadIdx.x;
    unsigned short* out = WCH + (size_t)r * 2048;
    if (r >= NN) {
        uint2 z; z.x = 0u; z.y = 0u;
        for (int i = tid; i < 512; i += 256) ((uint2*)out)[i] = z;
        return;
    }
    __shared__ float row[NN];
    __shared__ float red[256];
    const float* in = CW + (size_t)r * NN;
    float mx = -1e30f;
    for (int i = tid; i < NN; i += 256) { float v = in[i]; row[i] = v; mx = fmaxf(mx, v); }
    red[tid] = mx; __syncthreads();
    for (int s = 128; s > 0; s >>= 1) {
        if (tid < s) red[tid] = fmaxf(red[tid], red[tid + s]);
        __syncthreads();
    }
    mx = red[0]; __syncthreads();
    float sm = 0.f;
    for (int i = tid; i < NN; i += 256) { float e = __expf(row[i] - mx); row[i] = e; sm += e; }
    red[tid] = sm; __syncthreads();
    for (int s = 128; s > 0; s >>= 1) {
        if (tid < s) red[tid] += red[tid + s];
        __syncthreads();
    }
    float inv = 1.f / red[0];
    for (int i = tid; i < 2048; i += 256)
        out[i] = (i < NN) ? f2bf(row[i] * inv) : (unsigned short)0;
}

// ---------------- lin_in as tiled GEMM: rows=(n,t), K=32, 64 cols -> bf16 out ----------------
__global__ __launch_bounds__(256) void k_lin2(const float* __restrict__ XS,
                                              const float* __restrict__ W,
                                              const float* __restrict__ b,
                                              unsigned short* __restrict__ OUT) {
    __shared__ float Wt[FIN][68];   // [k][o]
    __shared__ float As[FIN][68];   // [k][row]
    int tid = threadIdx.x;
    int n = blockIdx.x;
    for (int i = tid; i < HH * FIN; i += 256) { int o = i >> 5, k = i & 31; Wt[k][o] = W[i]; }
    int row = tid >> 2, kq = tid & 3;   // row = t
    {
        const float4* src = (const float4*)(XS + ((size_t)row * NN + n) * FIN + kq * 8);
        float4 v0 = src[0], v1 = src[1];
        As[kq * 8 + 0][row] = v0.x; As[kq * 8 + 1][row] = v0.y;
        As[kq * 8 + 2][row] = v0.z; As[kq * 8 + 3][row] = v0.w;
        As[kq * 8 + 4][row] = v1.x; As[kq * 8 + 5][row] = v1.y;
        As[kq * 8 + 6][row] = v1.z; As[kq * 8 + 7][row] = v1.w;
    }
    __syncthreads();
    int tx = tid & 15, ty = tid >> 4;
    float acc[4][4] = {};
#pragma unroll
    for (int k = 0; k < FIN; ++k) {
        float4 av = *(const float4*)&As[k][ty * 4];
        float4 wv = *(const float4*)&Wt[k][tx * 4];
        acc[0][0] += av.x * wv.x; acc[0][1] += av.x * wv.y; acc[0][2] += av.x * wv.z; acc[0][3] += av.x * wv.w;
        acc[1][0] += av.y * wv.x; acc[1][1] += av.y * wv.y; acc[1][2] += av.y * wv.z; acc[1][3] += av.y * wv.w;
        acc[2][0] += av.z * wv.x; acc[2][1] += av.z * wv.y; acc[2][2] += av.z * wv.z; acc[2][3] += av.z * wv.w;
        acc[3][0] += av.w * wv.x; acc[3][1] += av.w * wv.y; acc[3][2] += av.w * wv.z; acc[3][3] += av.w * wv.w;
    }
    float4 bv = *(const float4*)(b + tx * 4);
#pragma unroll
    for (int ii = 0; ii < 4; ++ii) {
        float o0 = fmaxf(acc[ii][0] + bv.x, 0.f);
        float o1 = fmaxf(acc[ii][1] + bv.y, 0.f);
        float o2 = fmaxf(acc[ii][2] + bv.z, 0.f);
        float o3 = fmaxf(acc[ii][3] + bv.w, 0.f);
        unsigned int p0 = (unsigned int)f2bf(o0) | ((unsigned int)f2bf(o1) << 16);
        unsigned int p1 = (unsigned int)f2bf(o2) | ((unsigned int)f2bf(o3) << 16);
        uint2 pk; pk.x = p0; pk.y = p1;
        *(uint2*)(OUT + ((size_t)n * TT + ty * 4 + ii) * HH + tx * 4) = pk;
    }
}

// ---------------- transpose (bf16 in, bf16 out) ----------------
__global__ __launch_bounds__(256) void k_tr(const unsigned short* __restrict__ X,
                                            unsigned short* __restrict__ XT) {
    __shared__ unsigned short tile[64][65];
    int cb = blockIdx.x * 64;
    int kb = blockIdx.y * 64;
    int tid = threadIdx.x;
    int r = tid >> 2, cq = tid & 3;
    unsigned short vals[16];
    if (kb + r < NN) {
        const uint4* src = (const uint4*)(X + (size_t)(kb + r) * THL + cb + cq * 16);
        uint4 u0 = src[0], u1 = src[1];
        *(uint4*)vals = u0; *(uint4*)(vals + 8) = u1;
    } else {
#pragma unroll
        for (int j = 0; j < 16; ++j) vals[j] = 0;   // zero-fill pad rows
    }
#pragma unroll
    for (int j = 0; j < 16; ++j) tile[cq * 16 + j][r] = vals[j];
    __syncthreads();
    int cl = tid >> 2, kq = tid & 3;
    unsigned short tmp[16];
#pragma unroll
    for (int j = 0; j < 16; ++j) tmp[j] = tile[cl][kq * 16 + j];
    unsigned short* dst = XT + (size_t)(cb + cl) * 2048 + kb + kq * 16;
    *(uint4*)dst = *(uint4*)tmp;
    *(uint4*)(dst + 8) = *(uint4*)(tmp + 8);
}

// ---------------- bf16 MFMA GEMM: C(bf16)[2000,4096] = WCh @ X (via XAh_t) — R22 proven ----------------
__global__ __launch_bounds__(256, 1) void k_gemm_bf(const unsigned short* __restrict__ A,
                                                    const unsigned short* __restrict__ B,
                                                    unsigned short* __restrict__ CH) {
    __shared__ unsigned short As[128][64];   // 16 KB, linear
    __shared__ unsigned short Bs[128][64];
    int tid = threadIdx.x;
    int mb = blockIdx.y * 128, nb = blockIdx.x * 128;
    int w = tid >> 6, lane = tid & 63;
    int wr = w >> 1, wc = w & 1;
    int l15 = lane & 15, l4 = lane >> 4;
    f32x4 acc[4][4] = {};
    int r_base = w * 8 + (lane >> 3);
    int colu = (lane & 7) * 8;
    for (int kt = 0; kt < 32; ++kt) {
        __syncthreads();
#pragma unroll
        for (int c = 0; c < 4; ++c) {
            int row = c * 32 + r_base;
            gload_lds16(A + (size_t)(mb + row) * 2048 + kt * 64 + colu, &As[c * 32 + w * 8][0]);
            gload_lds16(B + (size_t)(nb + row) * 2048 + kt * 64 + colu, &Bs[c * 32 + w * 8][0]);
        }
        __syncthreads();
#pragma unroll
        for (int kk = 0; kk < 2; ++kk) {
            short8v af[4], bfr[4];
#pragma unroll
            for (int f = 0; f < 4; ++f) {
                af[f]  = *(const short8v*)&As[wr * 64 + f * 16 + l15][kk * 32 + l4 * 8];
                bfr[f] = *(const short8v*)&Bs[wc * 64 + f * 16 + l15][kk * 32 + l4 * 8];
            }
#pragma unroll
            for (int fm = 0; fm < 4; ++fm)
#pragma unroll
                for (int fn = 0; fn < 4; ++fn)
                    acc[fm][fn] = __builtin_amdgcn_mfma_f32_16x16x32_bf16(af[fm], bfr[fn], acc[fm][fn], 0, 0, 0);
        }
    }
    unsigned short* epi = (unsigned short*)(&As[0][0]) + (size_t)w * (16 * 72);
    int erow8 = lane >> 3;
    int ecol8 = lane & 7;
#pragma unroll
    for (int fm = 0; fm < 4; ++fm) {
        __syncthreads();
#pragma unroll
        for (int fn = 0; fn < 4; ++fn)
#pragma unroll
            for (int rr = 0; rr < 4; ++rr)
                epi[(l4 * 4 + rr) * 72 + fn * 16 + l15] = f2bf(acc[fm][fn][rr]);
        __syncthreads();
#pragma unroll
        for (int rh = 0; rh < 2; ++rh) {
            int lrow = rh * 8 + erow8;
            int grow = mb + wr * 64 + fm * 16 + lrow;
            if (grow < NN) {
                *(uint4*)(CH + (size_t)grow * THL + nb + wc * 64 + ecol8 * 8)
                    = *(const uint4*)&epi[lrow * 72 + ecol8 * 8];
            }
        }
    }
}

// ---------------- FUSED: fusion (K=128, both inputs bf16) + relu + xw0 GEMM -> xw0 bf16 ----------------
__global__ __launch_bounds__(256) void k_fusxw(const unsigned short* __restrict__ X,
                                               const unsigned short* __restrict__ XAH,
                                               const float* __restrict__ W,
                                               const float* __restrict__ b,
                                               const float* __restrict__ W0,
                                               unsigned short* __restrict__ OUT) {
    __shared__ float Wt[2 * HH][68];
    __shared__ float As[HH][68];
    int tid = threadIdx.x;
    size_t r0 = (size_t)blockIdx.x * 64;
    for (int i = tid; i < HH * 2 * HH; i += 256) { int o = i >> 7, k = i & 127; Wt[k][o] = W[i]; }
    int row = tid >> 2, kq = tid & 3;
    int tx = tid & 15, ty = tid >> 4;
    float acc[4][4] = {};
    __syncthreads();
    {
        const uint4* s = (const uint4*)(X + (r0 + row) * HH + kq * 16);
        uint4 u0 = s[0], u1 = s[1];
        unsigned short us[16];
        *(uint4*)us = u0; *(uint4*)(us + 8) = u1;
#pragma unroll
        for (int j = 0; j < 16; ++j)
            As[kq * 16 + j][row] = bf2f(us[j]);
    }
    __syncthreads();
#pragma unroll
    for (int k = 0; k < HH; ++k) {
        float4 av = *(const float4*)&As[k][ty * 4];
        float4 wv = *(const float4*)&Wt[k][tx * 4];
        acc[0][0] += av.x * wv.x; acc[0][1] += av.x * wv.y; acc[0][2] += av.x * wv.z; acc[0][3] += av.x * wv.w;
        acc[1][0] += av.y * wv.x; acc[1][1] += av.y * wv.y; acc[1][2] += av.y * wv.z; acc[1][3] += av.y * wv.w;
        acc[2][0] += av.z * wv.x; acc[2][1] += av.z * wv.y; acc[2][2] += av.z * wv.z; acc[2][3] += av.z * wv.w;
        acc[3][0] += av.w * wv.x; acc[3][1] += av.w * wv.y; acc[3][2] += av.w * wv.z; acc[3][3] += av.w * wv.w;
    }
    __syncthreads();
    {
        const uint4* s = (const uint4*)(XAH + (r0 + row) * HH + kq * 16);
        uint4 u0 = s[0], u1 = s[1];
        unsigned short us[16];
        *(uint4*)us = u0; *(uint4*)(us + 8) = u1;
#pragma unroll
        for (int j = 0; j < 16; ++j)
            As[kq * 16 + j][row] = bf2f(us[j]);
    }
    __syncthreads();
#pragma unroll
    for (int k = 0; k < HH; ++k) {
        float4 av = *(const float4*)&As[k][ty * 4];
        float4 wv = *(const float4*)&Wt[HH + k][tx * 4];
        acc[0][0] += av.x * wv.x; acc[0][1] += av.x * wv.y; acc[0][2] += av.x * wv.z; acc[0][3] += av.x * wv.w;
        acc[1][0] += av.y * wv.x; acc[1][1] += av.y * wv.y; acc[1][2] += av.y * wv.z; acc[1][3] += av.y * wv.w;
        acc[2][0] += av.z * wv.x; acc[2][1] += av.z * wv.y; acc[2][2] += av.z * wv.z; acc[2][3] += av.z * wv.w;
        acc[3][0] += av.w * wv.x; acc[3][1] += av.w * wv.y; acc[3][2] += av.w * wv.z; acc[3][3] += av.w * wv.w;
    }
    float4 bv = *(const float4*)(b + tx * 4);
    __syncthreads();   // all reads of As (phase-1 input) done before overwrite
#pragma unroll
    for (int ii = 0; ii < 4; ++ii) {
        As[tx * 4 + 0][ty * 4 + ii] = fmaxf(acc[ii][0] + bv.x, 0.f);
        As[tx * 4 + 1][ty * 4 + ii] = fmaxf(acc[ii][1] + bv.y, 0.f);
        As[tx * 4 + 2][ty * 4 + ii] = fmaxf(acc[ii][2] + bv.z, 0.f);
        As[tx * 4 + 3][ty * 4 + ii] = fmaxf(acc[ii][3] + bv.w, 0.f);
    }
    for (int i = tid; i < HH * HH; i += 256) { int o = i >> 6, k = i & 63; Wt[k][o] = W0[i]; }
    __syncthreads();
    // xw0 GEMM: K=64
    float a2[4][4] = {};
#pragma unroll
    for (int k = 0; k < HH; ++k) {
        float4 av = *(const float4*)&As[k][ty * 4];
        float4 wv = *(const float4*)&Wt[k][tx * 4];
        a2[0][0] += av.x * wv.x; a2[0][1] += av.x * wv.y; a2[0][2] += av.x * wv.z; a2[0][3] += av.x * wv.w;
        a2[1][0] += av.y * wv.x; a2[1][1] += av.y * wv.y; a2[1][2] += av.y * wv.z; a2[1][3] += av.y * wv.w;
        a2[2][0] += av.z * wv.x; a2[2][1] += av.z * wv.y; a2[2][2] += av.z * wv.z; a2[2][3] += av.z * wv.w;
        a2[3][0] += av.w * wv.x; a2[3][1] += av.w * wv.y; a2[3][2] += av.w * wv.z; a2[3][3] += av.w * wv.w;
    }
#pragma unroll
    for (int ii = 0; ii < 4; ++ii) {
        unsigned int p0 = (unsigned int)f2bf(a2[ii][0]) | ((unsigned int)f2bf(a2[ii][1]) << 16);
        unsigned int p1 = (unsigned int)f2bf(a2[ii][2]) | ((unsigned int)f2bf(a2[ii][3]) << 16);
        uint2 pk; pk.x = p0; pk.y = p1;
        *(uint2*)(OUT + (r0 + ty * 4 + ii) * HH + tx * 4) = pk;
    }
}

// ---------------- FUSED: agg (CSR, bf16) + bias + BN + relu + xw1 GEMM -> xw1 bf16 ----------------
__global__ __launch_bounds__(256) void k_aggxw(const unsigned short* __restrict__ XW,
                                               const int* __restrict__ off,
                                               const int* __restrict__ csr_src,
                                               const float* __restrict__ csr_nrm,
                                               const float* __restrict__ bias,
                                               const float* __restrict__ g,
                                               const float* __restrict__ bb,
                                               const float* __restrict__ m,
                                               const float* __restrict__ v,
                                               const float* __restrict__ W1,
                                               unsigned short* __restrict__ OUT) {
    __shared__ float Rs[HH][18];    // [k=h][row 0..15]
    __shared__ float Wt[HH][68];    // [k][o]
    int dst = blockIdx.x, ch = blockIdx.y, tid = threadIdx.x;
    int base = ch * 1024 + tid * 4;
    for (int i = tid; i < HH * HH; i += 256) { int o = i >> 6, k = i & 63; Wt[k][o] = W1[i]; }
    float4 acc = make_float4(0.f, 0.f, 0.f, 0.f);
    int beg = off[dst], end = off[dst + 1];
    for (int e = beg; e < end; ++e) {
        int src = csr_src[e];
        float w = csr_nrm[e];
        uint2 u = *(const uint2*)(XW + (size_t)src * THL + base);
        acc.x += w * bf2f((unsigned short)(u.x & 0xffff));
        acc.y += w * bf2f((unsigned short)(u.x >> 16));
        acc.z += w * bf2f((unsigned short)(u.y & 0xffff));
        acc.w += w * bf2f((unsigned short)(u.y >> 16));
    }
    int h0 = base & 63;             // = (tid&15)*4
    int rloc = tid >> 4;            // local row 0..15
    float4 bs = *(const float4*)(bias + h0);
    float4 gv = *(const float4*)(g + h0);
    float4 vv = *(const float4*)(v + h0);
    float4 mv = *(const float4*)(m + h0);
    float4 bv = *(const float4*)(bb + h0);
    Rs[h0 + 0][rloc] = fmaxf((acc.x + bs.x - mv.x) * rsqrtf(vv.x + EPSBN) * gv.x + bv.x, 0.f);
    Rs[h0 + 1][rloc] = fmaxf((acc.y + bs.y - mv.y) * rsqrtf(vv.y + EPSBN) * gv.y + bv.y, 0.f);
    Rs[h0 + 2][rloc] = fmaxf((acc.z + bs.z - mv.z) * rsqrtf(vv.z + EPSBN) * gv.z + bv.z, 0.f);
    Rs[h0 + 3][rloc] = fmaxf((acc.w + bs.w - mv.w) * rsqrtf(vv.w + EPSBN) * gv.w + bv.w, 0.f);
    __syncthreads();
    int c4 = tid & 15;
    float a2[4] = {0.f, 0.f, 0.f, 0.f};
#pragma unroll
    for (int k = 0; k < HH; ++k) {
        float a = Rs[k][rloc];
        float4 wv = *(const float4*)&Wt[k][c4 * 4];
        a2[0] += a * wv.x; a2[1] += a * wv.y; a2[2] += a * wv.z; a2[3] += a * wv.w;
    }
    size_t grow = (size_t)dst * TT + ch * 16 + rloc;
    unsigned int p0 = (unsigned int)f2bf(a2[0]) | ((unsigned int)f2bf(a2[1]) << 16);
    unsigned int p1 = (unsigned int)f2bf(a2[2]) | ((unsigned int)f2bf(a2[3]) << 16);
    uint2 pk; pk.x = p0; pk.y = p1;
    *(uint2*)(OUT + grow * HH + c4 * 4) = pk;
}

// ---------------- GCN aggregate (CSR, bf16 in) + bias + BN + relu -> bf16 out (GRU input) ----------------
__global__ __launch_bounds__(256) void k_agg(const unsigned short* __restrict__ XW,
                                             const int* __restrict__ off,
                                             const int* __restrict__ csr_src,
                                             const float* __restrict__ csr_nrm,
                                             const float* __restrict__ bias,
                                             const float* __restrict__ g,
                                             const float* __restrict__ bb,
                                             const float* __restrict__ m,
                                             const float* __restrict__ v,
                                             unsigned short* __restrict__ OUT) {
    int dst = blockIdx.x, ch = blockIdx.y, tid = threadIdx.x;
    int base = ch * 1024 + tid * 4;
    float4 acc = make_float4(0.f, 0.f, 0.f, 0.f);
    int beg = off[dst], end = off[dst + 1];
    for (int e = beg; e < end; ++e) {
        int src = csr_src[e];
        float w = csr_nrm[e];
        uint2 u = *(const uint2*)(XW + (size_t)src * THL + base);
        acc.x += w * bf2f((unsigned short)(u.x & 0xffff));
        acc.y += w * bf2f((unsigned short)(u.x >> 16));
        acc.z += w * bf2f((unsigned short)(u.y & 0xffff));
        acc.w += w * bf2f((unsigned short)(u.y >> 16));
    }
    int h0 = base & 63;
    float4 bs = *(const float4*)(bias + h0);
    float4 gv = *(const float4*)(g + h0);
    float4 vv = *(const float4*)(v + h0);
    float4 mv = *(const float4*)(m + h0);
    float4 bv = *(const float4*)(bb + h0);
    float o0 = fmaxf((acc.x + bs.x - mv.x) * rsqrtf(vv.x + EPSBN) * gv.x + bv.x, 0.f);
    float o1 = fmaxf((acc.y + bs.y - mv.y) * rsqrtf(vv.y + EPSBN) * gv.y + bv.y, 0.f);
    float o2 = fmaxf((acc.z + bs.z - mv.z) * rsqrtf(vv.z + EPSBN) * gv.z + bv.z, 0.f);
    float o3 = fmaxf((acc.w + bs.w - mv.w) * rsqrtf(vv.w + EPSBN) * gv.w + bv.w, 0.f);
    unsigned int p0 = (unsigned int)f2bf(o0) | ((unsigned int)f2bf(o1) << 16);
    unsigned int p1 = (unsigned int)f2bf(o2) | ((unsigned int)f2bf(o3) << 16);
    uint2 pk; pk.x = p0; pk.y = p1;
    *(uint2*)(OUT + (size_t)dst * THL + base) = pk;
}

// ---------------- MFMA 2-layer GRU: R27 = 8-wave layer-split + reg-h ----------------
// 512 threads: waves 0-3 compute layer0 (col-group w), waves 4-7 layer1 (col-group w-4).
// Same skew scheme as R22 (at step t: L0 -> h0(t), L1 -> h1(t-1), both from captured
// h0(t-1)); same capture/barrier structure -> bit-identical math. Each SIMD now hosts
// 2 waves (one L0, one L1) so their latency bubbles (ds_read, exp, acc-read) overlap.
// fp32 h in registers (each (node,jr) thread-owned); bf16 h stays in LDS (cross-wave).
__global__ __launch_bounds__(512, 1) void k_gruM(const unsigned short* __restrict__ IN,
                                                 const float* __restrict__ wih0, const float* __restrict__ whh0,
                                                 const float* __restrict__ bih0, const float* __restrict__ bhh0,
                                                 const float* __restrict__ wih1, const float* __restrict__ whh1,
                                                 const float* __restrict__ bih1, const float* __restrict__ bhh1,
                                                 float* __restrict__ hout) {
    __shared__ unsigned short hb0[NB][72];
    __shared__ unsigned short hb1[NB][72];
    int tid = threadIdx.x;
    int w = tid >> 6, lane = tid & 63;
    int l15 = lane & 15, l4 = lane >> 4;
    int nb0 = blockIdx.x * NB;
    bool isL0 = (w < 4);
    int cg = isL0 ? w : (w - 4);
    int jr = 16 * cg + l15;
    const float* Wx = isL0 ? wih0 : wih1;
    const float* Wh = isL0 ? whh0 : whh1;
    short8v bwx[3][2], bwh[3][2];
#pragma unroll
    for (int g = 0; g < 3; ++g)
#pragma unroll
        for (int kk = 0; kk < 2; ++kk) {
            const float* sx = Wx + (size_t)(64 * g + jr) * HH + kk * 32 + l4 * 8;
            float4 x0 = *(const float4*)sx;
            float4 x1 = *(const float4*)(sx + 4);
            short8v fx;
            fx[0] = (short)f2bf(x0.x); fx[1] = (short)f2bf(x0.y);
            fx[2] = (short)f2bf(x0.z); fx[3] = (short)f2bf(x0.w);
            fx[4] = (short)f2bf(x1.x); fx[5] = (short)f2bf(x1.y);
            fx[6] = (short)f2bf(x1.z); fx[7] = (short)f2bf(x1.w);
            bwx[g][kk] = fx;
            const float* sh = Wh + (size_t)(64 * g + jr) * HH + kk * 32 + l4 * 8;
            float4 h0v = *(const float4*)sh;
            float4 h1v = *(const float4*)(sh + 4);
            short8v fh;
            fh[0] = (short)f2bf(h0v.x); fh[1] = (short)f2bf(h0v.y);
            fh[2] = (short)f2bf(h0v.z); fh[3] = (short)f2bf(h0v.w);
            fh[4] = (short)f2bf(h1v.x); fh[5] = (short)f2bf(h1v.y);
            fh[6] = (short)f2bf(h1v.z); fh[7] = (short)f2bf(h1v.w);
            bwh[g][kk] = fh;
        }
    const float* bi = isL0 ? bih0 : bih1;
    const float* bh = isL0 ? bhh0 : bhh1;
    float br  = bi[jr] + bh[jr];
    float bz  = bi[64 + jr] + bh[64 + jr];
    float bn  = bi[128 + jr];
    float hnb = bh[128 + jr];
    float rh[4] = {0.f, 0.f, 0.f, 0.f};   // fp32 h for (node=l4*4+i, col jr), thread-owned
    for (int i = tid; i < NB * 72; i += 512) {
        ((unsigned short*)hb0)[i] = 0;
        ((unsigned short*)hb1)[i] = 0;
    }
    __syncthreads();
    const unsigned short* xb = IN + (size_t)(nb0 + l15) * (TT * HH);
    uint4 xu0, xu1;
    if (isL0) {   // only L0 waves consume x
        xu0 = *(const uint4*)(xb + l4 * 8);
        xu1 = *(const uint4*)(xb + 32 + l4 * 8);
    }
#pragma unroll 1
    for (int t = 0; t <= TT; ++t) {
        bool act = isL0 ? (t < TT) : (t >= 1);
        // capture: aA = x(t) [L0] or h0(t-1) [L1]; aB = h0(t-1) [L0] or h1(t-2) [L1]
        short8v aA[2], aB[2];
        if (isL0) {
            aA[0] = *(const short8v*)&xu0;
            aA[1] = *(const short8v*)&xu1;
            aB[0] = *(const short8v*)&hb0[l15][l4 * 8];
            aB[1] = *(const short8v*)&hb0[l15][32 + l4 * 8];
        } else {
            aA[0] = *(const short8v*)&hb0[l15][l4 * 8];
            aA[1] = *(const short8v*)&hb0[l15][32 + l4 * 8];
            aB[0] = *(const short8v*)&hb1[l15][l4 * 8];
            aB[1] = *(const short8v*)&hb1[l15][32 + l4 * 8];
        }
        __syncthreads();   // captures done before this step's writes
        if (isL0 && t + 1 < TT) {
            const unsigned short* xs = xb + (size_t)(t + 1) * HH;
            xu0 = *(const uint4*)(xs + l4 * 8);
            xu1 = *(const uint4*)(xs + 32 + l4 * 8);
        }
        if (act) {
            f32x4 gr = { br, br, br, br };
            f32x4 gz = { bz, bz, bz, bz };
            f32x4 gn = { bn, bn, bn, bn };
            f32x4 hr = { 0.f, 0.f, 0.f, 0.f };
            f32x4 hz = { 0.f, 0.f, 0.f, 0.f };
            f32x4 hn = { hnb, hnb, hnb, hnb };
#pragma unroll
            for (int kk = 0; kk < 2; ++kk) {
                gr = __builtin_amdgcn_mfma_f32_16x16x32_bf16(aA[kk], bwx[0][kk], gr, 0, 0, 0);
                gz = __builtin_amdgcn_mfma_f32_16x16x32_bf16(aA[kk], bwx[1][kk], gz, 0, 0, 0);
                gn = __builtin_amdgcn_mfma_f32_16x16x32_bf16(aA[kk], bwx[2][kk], gn, 0, 0, 0);
                hr = __builtin_amdgcn_mfma_f32_16x16x32_bf16(aB[kk], bwh[0][kk], hr, 0, 0, 0);
                hz = __builtin_amdgcn_mfma_f32_16x16x32_bf16(aB[kk], bwh[1][kk], hz, 0, 0, 0);
                hn = __builtin_amdgcn_mfma_f32_16x16x32_bf16(aB[kk], bwh[2][kk], hn, 0, 0, 0);
            }
            unsigned short* hbw = isL0 ? &hb0[0][0] : &hb1[0][0];
#pragma unroll
            for (int i = 0; i < 4; ++i) {
                int node = l4 * 4 + i;
                float r = fsigmoid(gr[i] + hr[i]);
                float z = fsigmoid(gz[i] + hz[i]);
                float nn2 = ftanh(gn[i] + r * hn[i]);
                float hv = (1.f - z) * nn2 + z * rh[i];
                rh[i] = hv;
                hbw[node * 72 + jr] = f2bf(hv);
            }
        }
        __syncthreads();   // writes visible before next step's captures
    }
    if (!isL0) {   // L1 waves own the final h1
#pragma unroll
        for (int i = 0; i < 4; ++i) {
            int node = l4 * 4 + i;
            hout[(size_t)(nb0 + node) * HH + jr] = rh[i];
        }
    }
}

// ---------------- head: BN + relu + linear + log_softmax ----------------
__global__ __launch_bounds__(256) void k_head(const float* __restrict__ Hf,
                                              const float* __restrict__ g, const float* __restrict__ b,
                                              const float* __restrict__ m, const float* __restrict__ v,
                                              const float* __restrict__ W, const float* __restrict__ wb,
                                              float* __restrict__ out) {
    __shared__ float hb[4][HH];
    __shared__ float lg[4][CC];
    int tid = threadIdx.x;
    int n0 = blockIdx.x * 4;
    int wv = tid >> 6, lane = tid & 63;
    int n = n0 + wv;
    float x = Hf[(size_t)n * HH + lane];
    x = (x - m[lane]) * rsqrtf(v[lane] + EPSBN) * g[lane] + b[lane];
    hb[wv][lane] = fmaxf(x, 0.f);
    __syncthreads();
    if (tid < 4 * CC) {
        int nn = tid / CC, c = tid % CC;
        float acc = wb[c];
        for (int f = 0; f < HH; ++f) acc += hb[nn][f] * W[c * HH + f];
        lg[nn][c] = acc;
    }
    __syncthreads();
    if (tid < 4 * CC) {
        int nn = tid / CC, c = tid % CC;
        float mx = -1e30f;
#pragma unroll
        for (int i = 0; i < CC; ++i) mx = fmaxf(mx, lg[nn][i]);
        float s = 0.f;
#pragma unroll
        for (int i = 0; i < CC; ++i) s += __expf(lg[nn][i] - mx);
        out[(size_t)(n0 + nn) * CC + c] = lg[nn][c] - mx - __logf(s);
    }
}

// ---------------- launch ----------------
extern "C" void kernel_launch(void* const* d_in, const int* in_sizes, int n_in,
                              void* d_out, int out_size, void* d_ws, size_t ws_size,
                              hipStream_t stream) {
    const float* x_seq     = (const float*)d_in[0];
    const int*   edge_idx  = (const int*)d_in[1];
    const float* edge_w    = (const float*)d_in[2];
    const float* causal_w  = (const float*)d_in[3];
    const float* lin_in_w  = (const float*)d_in[4];
    const float* lin_in_b  = (const float*)d_in[5];
    const float* fusion_w  = (const float*)d_in[6];
    const float* fusion_b  = (const float*)d_in[7];
    const float* gcn_w0    = (const float*)d_in[8];
    const float* gcn_b0    = (const float*)d_in[9];
    const float* gcn_w1    = (const float*)d_in[10];
    const float* gcn_b1    = (const float*)d_in[11];
    const float* bn0_g = (const float*)d_in[12], *bn0_b = (const float*)d_in[13];
    const float* bn0_m = (const float*)d_in[14], *bn0_v = (const float*)d_in[15];
    const float* bn1_g = (const float*)d_in[16], *bn1_b = (const float*)d_in[17];
    const float* bn1_m = (const float*)d_in[18], *bn1_v = (const float*)d_in[19];
    const float* wih0 = (const float*)d_in[20], *whh0 = (const float*)d_in[21];
    const float* bih0 = (const float*)d_in[22], *bhh0 = (const float*)d_in[23];
    const float* wih1 = (const float*)d_in[24], *whh1 = (const float*)d_in[25];
    const float* bih1 = (const float*)d_in[26], *bhh1 = (const float*)d_in[27];
    const float* bno_g = (const float*)d_in[28], *bno_b = (const float*)d_in[29];
    const float* bno_m = (const float*)d_in[30], *bno_v = (const float*)d_in[31];
    const float* lout_w = (const float*)d_in[32], *lout_b = (const float*)d_in[33];
    float* out = (float*)d_out;

    float* wsf = (float*)d_ws;
    unsigned short* WCH = (unsigned short*)(wsf + OFF_WC);
    unsigned short* XLH = (unsigned short*)(wsf + OFF_XA);   // lin_in bf16 [128000][64]
    unsigned short* XAT = (unsigned short*)(wsf + OFF_XC);   // bf16 XAh_t [4096][2048]
    unsigned short* XBH = (unsigned short*)(wsf + OFF_XB);   // bf16: x_agg, then xw0 (in place)
    unsigned short* XW1 = (unsigned short*)(wsf + OFF_XA);   // bf16 xw1 (XA region, post-fusxw)
    unsigned short* XCH = (unsigned short*)(wsf + OFF_XC);   // bf16 agg1 out (GRU input)
    float* DEG = wsf + OFF_DEG;
    int* CNT   = (int*)(wsf + OFF_CNT);
    int* CUR   = (int*)(wsf + OFF_CUR);
    int* OFFP  = (int*)(wsf + OFF_OFF);
    int* CSRS  = (int*)(wsf + OFF_CSRS);
    float* CSRN = wsf + OFF_CSRN;
    float* HST  = wsf + OFF_HST;

    // CSR + degree build
    k_zero<<<8, 256, 0, stream>>>(CNT, CUR, DEG);
    k_count<<<(ETOT + 255) / 256, 256, 0, stream>>>(edge_idx, edge_w, CNT, DEG);
    k_scan<<<1, 1024, 0, stream>>>(CNT, OFFP);
    k_fill<<<(ETOT + 255) / 256, 256, 0, stream>>>(edge_idx, edge_w, DEG, OFFP, CUR, CSRS, CSRN);

    // softmax (grid 2048: rows >= NN zero-fill; replaces WCH memset)
    k_softmax<<<2048, 256, 0, stream>>>(causal_w, WCH);
    // lin_in -> XLH bf16 [N*T][H]
    k_lin2<<<NN, 256, 0, stream>>>(x_seq, lin_in_w, lin_in_b, XLH);
    // transpose: XLH -> XAh_t bf16 [4096][2048] (zero-fill pad rows)
    dim3 tg(THL / 64, 2048 / 64);
    k_tr<<<tg, 256, 0, stream>>>(XLH, XAT);
    // x_agg = WCh @ X (MFMA bf16) -> XBH (bf16)
    dim3 gg(THL / 128, 2048 / 128);
    k_gemm_bf<<<gg, 256, 0, stream>>>(WCH, XAT, XBH);
    // fusion + relu + xw0 -> XBH (bf16, in place)
    k_fusxw<<<NN, 256, 0, stream>>>(XLH, XBH, fusion_w, fusion_b, gcn_w0, XBH);
    // agg0 + BN0 + relu + xw1 -> XW1 (bf16, XA region)
    dim3 ag(NN, 4);
    k_aggxw<<<ag, 256, 0, stream>>>(XBH, OFFP, CSRS, CSRN, gcn_b0, bn0_g, bn0_b, bn0_m, bn0_v,
                                    gcn_w1, XW1);
    // agg1 + BN1 + relu -> XCH (bf16, GRU input)
    k_agg<<<ag, 256, 0, stream>>>(XW1, OFFP, CSRS, CSRN, gcn_b1, bn1_g, bn1_b, bn1_m, bn1_v, XCH);

    // MFMA 2-layer GRU (8-wave layer-split): XCH -> final h in HST (125 blocks x 512)
    k_gruM<<<NN / NB, 512, 0, stream>>>(XCH, wih0, whh0, bih0, bhh0,
                                        wih1, whh1, bih1, bhh1, HST);

    // head
    k_head<<<NN / 4, 256, 0, stream>>>(HST, bno_g, bno_b, bno_m, bno_v, lout_w, lout_b, out);
}